// Round 6
// baseline (826.966 us; speedup 1.0000x reference)
//
#include <hip/hip_runtime.h>
#include <math.h>

// ---------------------------------------------------------------------------
// Problem constants (from reference)
// ---------------------------------------------------------------------------
#define HIDDEN 64
#define HEADS 2
#define NCOLS 448          // GEMM logical cols: q(128) k(128) v(128) s(64)
#define QS_COLS 192        // fp32: q0 q1 (128) + skip (64)
#define KV_COLS 256        // fp32: k0 | k1 | v0 | v1 (64 each)
#define N_GRAPHS 64
#define LN_EPS 1e-5f

// ---------------------------------------------------------------------------
// Weight pack: Wcat[K][448] = [Wq*0.125 | Wk | Wv | Ws], bcat[448]
// (1/sqrt(64) folded into q — exact power-of-2 scale, bitwise-neutral)
// ---------------------------------------------------------------------------
__global__ void pack_kernel(const float* __restrict__ Wq, const float* __restrict__ Wk,
                            const float* __restrict__ Wv, const float* __restrict__ Ws,
                            const float* __restrict__ bq, const float* __restrict__ bk,
                            const float* __restrict__ bv, const float* __restrict__ bs,
                            float* __restrict__ Wcat, float* __restrict__ bcat, int K)
{
    int idx = blockIdx.x * 256 + threadIdx.x;
    int total = K * NCOLS;
    if (idx < total) {
        int r = idx / NCOLS, c = idx - r * NCOLS;
        float v;
        if      (c < 128) v = Wq[r * 128 + c] * 0.125f;
        else if (c < 256) v = Wk[r * 128 + (c - 128)];
        else if (c < 384) v = Wv[r * 128 + (c - 256)];
        else              v = Ws[r * 64  + (c - 384)];
        Wcat[idx] = v;
    }
    if (idx < NCOLS) {
        float b;
        if      (idx < 128) b = bq[idx] * 0.125f;
        else if (idx < 256) b = bk[idx - 128];
        else if (idx < 384) b = bv[idx - 256];
        else                b = bs[idx - 384];
        bcat[idx] = b;
    }
}

// ---------------------------------------------------------------------------
// Layer-0 tiled GEMM (K=128): C = A[M,128] @ Wcat[128,448] + bias
// BM=256, BN=64, BK=16, 256 threads, 16x4 microtile / thread.
// Split epilogue: q/skip -> qs fp32 [192], k/v -> kv fp32 [256].
// ---------------------------------------------------------------------------
#define BM 256
#define BN 64
#define BK 16

__global__ __launch_bounds__(256) void gemm_bias_kernel(
    const float* __restrict__ A, const float* __restrict__ B,
    const float* __restrict__ bias, float* __restrict__ qs,
    float* __restrict__ kv, int M, int K)
{
    __shared__ __align__(16) float As[BK][BM + 4]; // k-major (transposed) A tile
    __shared__ __align__(16) float Bs[BK][BN];

    int tid = threadIdx.x;
    int tx = tid & 15;    // 0..15 -> 4 cols each
    int ty = tid >> 4;    // 0..15 -> 16 rows each
    int row0 = blockIdx.y * BM;
    int col0 = blockIdx.x * BN;

    float acc[16][4] = {};

    for (int k0 = 0; k0 < K; k0 += BK) {
        #pragma unroll
        for (int i = 0; i < 4; ++i) {
            int f   = tid + i * 256;          // float4 id
            int m   = f >> 2;                 // 0..255
            int kc  = f & 3;                  // 0..3 (k-chunk of 4)
            int gr  = row0 + m;
            float4 v = make_float4(0.f, 0.f, 0.f, 0.f);
            if (gr < M) v = *(const float4*)&A[(size_t)gr * K + k0 + kc * 4];
            As[kc * 4 + 0][m] = v.x;
            As[kc * 4 + 1][m] = v.y;
            As[kc * 4 + 2][m] = v.z;
            As[kc * 4 + 3][m] = v.w;
        }
        {
            int kk = tid >> 4;
            int c4 = tid & 15;
            *(float4*)&Bs[kk][c4 * 4] =
                *(const float4*)&B[(size_t)(k0 + kk) * NCOLS + col0 + c4 * 4];
        }
        __syncthreads();
        #pragma unroll
        for (int kk = 0; kk < BK; ++kk) {
            float4 t0 = *(const float4*)&As[kk][ty * 16 + 0];
            float4 t1 = *(const float4*)&As[kk][ty * 16 + 4];
            float4 t2 = *(const float4*)&As[kk][ty * 16 + 8];
            float4 t3 = *(const float4*)&As[kk][ty * 16 + 12];
            float4 b4 = *(const float4*)&Bs[kk][tx * 4];
            float av[16] = {t0.x, t0.y, t0.z, t0.w, t1.x, t1.y, t1.z, t1.w,
                            t2.x, t2.y, t2.z, t2.w, t3.x, t3.y, t3.z, t3.w};
            float bv[4] = {b4.x, b4.y, b4.z, b4.w};
            #pragma unroll
            for (int i = 0; i < 16; ++i)
                #pragma unroll
                for (int j = 0; j < 4; ++j)
                    acc[i][j] = fmaf(av[i], bv[j], acc[i][j]);
        }
        __syncthreads();
    }

    float4 bsv = *(const float4*)&bias[col0 + tx * 4];
    int part = col0 >> 6;   // 0,1: q   2..5: k0,k1,v0,v1   6: skip
    #pragma unroll
    for (int i = 0; i < 16; ++i) {
        int r = row0 + ty * 16 + i;
        if (r >= M) continue;
        float4 o = make_float4(acc[i][0] + bsv.x, acc[i][1] + bsv.y,
                               acc[i][2] + bsv.z, acc[i][3] + bsv.w);
        if (part < 2) {
            *(float4*)&qs[(size_t)r * QS_COLS + col0 + tx * 4] = o;
        } else if (part == 6) {
            *(float4*)&qs[(size_t)r * QS_COLS + 128 + tx * 4] = o;
        } else {
            *(float4*)&kv[(size_t)r * KV_COLS + (part - 2) * 64 + tx * 4] = o;
        }
    }
}

// ---------------------------------------------------------------------------
// Layers 1-2 GEMM (K=64): entire B [64][448] lives in LDS (114.7 KB) + one
// 64-row A chunk (16 KB) = 128 KiB total. 512 threads: wave w -> 8 rows,
// lane -> cols {lane + 64j}. A-reads are wave-uniform (LDS broadcast, free);
// B-reads conflict-free. A and B each loaded from HBM exactly once.
// ---------------------------------------------------------------------------
__global__ __launch_bounds__(512) void gemm_persistB_kernel(
    const float* __restrict__ A,     // [M][64]
    const float* __restrict__ B,     // [64][448] packed
    const float* __restrict__ bias,  // [448]
    float* __restrict__ qs, float* __restrict__ kv, int M)
{
    __shared__ float Bs[64][NCOLS];  // 114,688 B
    __shared__ float As[64][64];     //  16,384 B

    int t    = threadIdx.x;
    int lane = t & 63;
    int wv   = t >> 6;               // 0..7

    // load all of B once (7168 float4s, coalesced)
    for (int i = t; i < (64 * NCOLS) / 4; i += 512) {
        int k  = i / (NCOLS / 4);
        int c4 = i - k * (NCOLS / 4);
        *(float4*)&Bs[k][c4 * 4] = *(const float4*)&B[(size_t)k * NCOLS + c4 * 4];
    }
    float bj[7];
    #pragma unroll
    for (int j = 0; j < 7; ++j) bj[j] = bias[lane + 64 * j];
    __syncthreads();

    int nchunks = (M + 63) / 64;
    for (int c = blockIdx.x; c < nchunks; c += gridDim.x) {
        int row0 = c * 64;
        // stage A chunk [64][64]: 1024 float4s, 2 per thread
        #pragma unroll
        for (int i = 0; i < 2; ++i) {
            int f  = t + i * 512;
            int r  = f >> 4;
            int c4 = f & 15;
            float4 v = make_float4(0.f, 0.f, 0.f, 0.f);
            if (row0 + r < M) v = *(const float4*)&A[(size_t)(row0 + r) * 64 + c4 * 4];
            *(float4*)&As[r][c4 * 4] = v;
        }
        __syncthreads();

        float acc[8][7] = {};
        #pragma unroll 4
        for (int k = 0; k < 64; ++k) {
            float a[8];
            #pragma unroll
            for (int r = 0; r < 8; ++r) a[r] = As[wv * 8 + r][k];   // broadcast
            float b[7];
            #pragma unroll
            for (int j = 0; j < 7; ++j) b[j] = Bs[k][lane + 64 * j];
            #pragma unroll
            for (int r = 0; r < 8; ++r)
                #pragma unroll
                for (int j = 0; j < 7; ++j)
                    acc[r][j] = fmaf(a[r], b[j], acc[r][j]);
        }
        __syncthreads();   // before next chunk overwrites As

        #pragma unroll
        for (int r = 0; r < 8; ++r) {
            int row = row0 + wv * 8 + r;
            if (row >= M) continue;
            #pragma unroll
            for (int j = 0; j < 7; ++j) {
                float o = acc[r][j] + bj[j];
                if (j < 2)       qs[(size_t)row * QS_COLS + lane + 64 * j] = o;
                else if (j == 6) qs[(size_t)row * QS_COLS + 128 + lane]    = o;
                else             kv[(size_t)row * KV_COLS + (j - 2) * 64 + lane] = o;
            }
        }
    }
}

// ---------------------------------------------------------------------------
// CSR build: histogram -> 3-kernel parallel scan -> scatter
// ---------------------------------------------------------------------------
__global__ void hist_kernel(const int* __restrict__ dst, int* __restrict__ counts, int E)
{
    int i = blockIdx.x * 256 + threadIdx.x;
    if (i < E) atomicAdd(&counts[dst[i]], 1);
}

__global__ __launch_bounds__(256) void block_reduce_kernel(
    const int* __restrict__ counts, int* __restrict__ bsum, int N)
{
    __shared__ int s[256];
    int t = threadIdx.x;
    int i = blockIdx.x * 256 + t;
    s[t] = (i < N) ? counts[i] : 0;
    __syncthreads();
    #pragma unroll
    for (int o = 128; o; o >>= 1) {
        if (t < o) s[t] += s[t + o];
        __syncthreads();
    }
    if (t == 0) bsum[blockIdx.x] = s[0];
}

__global__ __launch_bounds__(256) void scan_partials_kernel(
    const int* __restrict__ bsum, int* __restrict__ boff, int nb, int* __restrict__ rowN)
{
    __shared__ int s[256];
    int t = threadIdx.x;
    int v = (t < nb) ? bsum[t] : 0;
    s[t] = v;
    __syncthreads();
    #pragma unroll
    for (int o = 1; o < 256; o <<= 1) {
        int x = (t >= o) ? s[t - o] : 0;
        __syncthreads();
        s[t] += x;
        __syncthreads();
    }
    if (t < nb) boff[t] = s[t] - v;     // exclusive
    if (t == nb - 1) rowN[0] = s[t];    // total = row_ptr[N]
}

__global__ __launch_bounds__(256) void block_scan_kernel(
    const int* __restrict__ counts, const int* __restrict__ boff,
    int* __restrict__ row_ptr, int* __restrict__ cursor, int N)
{
    __shared__ int s[256];
    int t = threadIdx.x;
    int i = blockIdx.x * 256 + t;
    int v = (i < N) ? counts[i] : 0;
    s[t] = v;
    __syncthreads();
    #pragma unroll
    for (int o = 1; o < 256; o <<= 1) {
        int x = (t >= o) ? s[t - o] : 0;
        __syncthreads();
        s[t] += x;
        __syncthreads();
    }
    if (i < N) {
        int excl = s[t] - v + boff[blockIdx.x];
        row_ptr[i] = excl;
        cursor[i]  = excl;
    }
}

__global__ void scatter_kernel(const int* __restrict__ ei, int* __restrict__ cursor,
                               int* __restrict__ src_sorted, int E)
{
    int i = blockIdx.x * 256 + threadIdx.x;
    if (i < E) {
        int d = ei[E + i];                    // dst
        int pos = atomicAdd(&cursor[d], 1);
        src_sorted[pos] = ei[i];              // src
    }
}

// ---------------------------------------------------------------------------
// DPP 16-lane sum (pure VALU)
// ---------------------------------------------------------------------------
__device__ __forceinline__ float dpp_sum16(float x)
{
    float t;
    t = __int_as_float(__builtin_amdgcn_mov_dpp(__float_as_int(x), 0xB1,  0xF, 0xF, true)); x += t; // xor 1
    t = __int_as_float(__builtin_amdgcn_mov_dpp(__float_as_int(x), 0x4E,  0xF, 0xF, true)); x += t; // xor 2
    t = __int_as_float(__builtin_amdgcn_mov_dpp(__float_as_int(x), 0x141, 0xF, 0xF, true)); x += t; // half-mirror
    t = __int_as_float(__builtin_amdgcn_mov_dpp(__float_as_int(x), 0x140, 0xF, 0xF, true)); x += t; // row-mirror
    return x;
}

// ---------------------------------------------------------------------------
// Fused edge kernel: one wave per dst node, 4 edge-groups x 16 lanes.
// R3-PROVEN loop: direct src_sorted[e] loads (NO shfl index preload — shfl
// from divergently-inactive lanes is undefined on CDNA and was the R4/R5
// accuracy bug). Register double-buffer, DPP dot-reduce, flash merge,
// head-mean + skip + ReLU + optional LN.
// ---------------------------------------------------------------------------
__global__ __launch_bounds__(256) void edge_conv_kernel(
    const float* __restrict__ qs, const float* __restrict__ kv,
    const int* __restrict__ row_ptr, const int* __restrict__ src_sorted,
    const float* __restrict__ gamma, const float* __restrict__ beta,
    float* __restrict__ hout, int N, int do_ln)
{
    int wave = threadIdx.x >> 6;
    int lane = threadIdx.x & 63;
    int g    = lane >> 4;        // edge-group 0..3
    int sub  = lane & 15;        // dim-chunk 0..15 (4 dims each)
    int node = blockIdx.x * 4 + wave;
    if (node >= N) return;

    const float* qb = qs + (size_t)node * QS_COLS;
    float4 q0 = *(const float4*)&qb[sub * 4];        // pre-scaled by 1/8
    float4 q1 = *(const float4*)&qb[64 + sub * 4];

    int e0 = row_ptr[node], e1 = row_ptr[node + 1];
    int deg = e1 - e0;

    float  m0 = -1e30f, m1 = -1e30f;
    float  s0 = 0.f, s1 = 0.f;
    float4 a0 = make_float4(0.f, 0.f, 0.f, 0.f);
    float4 a1 = make_float4(0.f, 0.f, 0.f, 0.f);

    int  e    = e0 + g;
    bool have = (e < e1);
    float4 k0c, k1c, v0c, v1c;
    if (have) {
        int j = src_sorted[e];
        const float* jb = kv + (size_t)j * KV_COLS;
        k0c = *(const float4*)&jb[sub * 4];
        k1c = *(const float4*)&jb[64 + sub * 4];
        v0c = *(const float4*)&jb[128 + sub * 4];
        v1c = *(const float4*)&jb[192 + sub * 4];
    }

    while (have) {
        int  en    = e + 4;
        bool haven = (en < e1);
        float4 k0n, k1n, v0n, v1n;
        if (haven) {
            int jn = src_sorted[en];
            const float* jbn = kv + (size_t)jn * KV_COLS;
            k0n = *(const float4*)&jbn[sub * 4];
            k1n = *(const float4*)&jbn[64 + sub * 4];
            v0n = *(const float4*)&jbn[128 + sub * 4];
            v1n = *(const float4*)&jbn[192 + sub * 4];
        }

        float p0 = fmaf(q0.w, k0c.w, fmaf(q0.z, k0c.z, fmaf(q0.y, k0c.y, q0.x * k0c.x)));
        float p1 = fmaf(q1.w, k1c.w, fmaf(q1.z, k1c.z, fmaf(q1.y, k1c.y, q1.x * k1c.x)));
        float sc0 = dpp_sum16(p0);
        float sc1 = dpp_sum16(p1);

        float nm0 = fmaxf(m0, sc0);
        float f0  = __expf(m0 - nm0);
        float w0  = __expf(sc0 - nm0);
        s0 = fmaf(s0, f0, w0);
        a0.x = fmaf(a0.x, f0, w0 * v0c.x);
        a0.y = fmaf(a0.y, f0, w0 * v0c.y);
        a0.z = fmaf(a0.z, f0, w0 * v0c.z);
        a0.w = fmaf(a0.w, f0, w0 * v0c.w);
        m0 = nm0;

        float nm1 = fmaxf(m1, sc1);
        float f1  = __expf(m1 - nm1);
        float w1  = __expf(sc1 - nm1);
        s1 = fmaf(s1, f1, w1);
        a1.x = fmaf(a1.x, f1, w1 * v1c.x);
        a1.y = fmaf(a1.y, f1, w1 * v1c.y);
        a1.z = fmaf(a1.z, f1, w1 * v1c.z);
        a1.w = fmaf(a1.w, f1, w1 * v1c.w);
        m1 = nm1;

        k0c = k0n; k1c = k1n; v0c = v0n; v1c = v1n;
        e = en; have = haven;
    }

    // merge flash states across the 4 groups (xor 16, then 32)
    #pragma unroll
    for (int offm = 16; offm <= 32; offm <<= 1) {
        float mo0 = __shfl_xor(m0, offm);
        float so0 = __shfl_xor(s0, offm);
        float4 ao0;
        ao0.x = __shfl_xor(a0.x, offm); ao0.y = __shfl_xor(a0.y, offm);
        ao0.z = __shfl_xor(a0.z, offm); ao0.w = __shfl_xor(a0.w, offm);
        float nm = fmaxf(m0, mo0);
        float fa = __expf(m0 - nm), fb = __expf(mo0 - nm);
        s0 = s0 * fa + so0 * fb;
        a0.x = a0.x * fa + ao0.x * fb; a0.y = a0.y * fa + ao0.y * fb;
        a0.z = a0.z * fa + ao0.z * fb; a0.w = a0.w * fa + ao0.w * fb;
        m0 = nm;

        float mo1 = __shfl_xor(m1, offm);
        float so1 = __shfl_xor(s1, offm);
        float4 ao1;
        ao1.x = __shfl_xor(a1.x, offm); ao1.y = __shfl_xor(a1.y, offm);
        ao1.z = __shfl_xor(a1.z, offm); ao1.w = __shfl_xor(a1.w, offm);
        nm = fmaxf(m1, mo1);
        fa = __expf(m1 - nm); fb = __expf(mo1 - nm);
        s1 = s1 * fa + so1 * fb;
        a1.x = a1.x * fa + ao1.x * fb; a1.y = a1.y * fa + ao1.y * fb;
        a1.z = a1.z * fa + ao1.z * fb; a1.w = a1.w * fa + ao1.w * fb;
        m1 = nm;
    }

    float4 skip = *(const float4*)&qb[128 + sub * 4];
    float4 o;
    if (deg > 0) {
        float r0 = 0.5f / s0, r1 = 0.5f / s1;
        o.x = a0.x * r0 + a1.x * r1 + skip.x;
        o.y = a0.y * r0 + a1.y * r1 + skip.y;
        o.z = a0.z * r0 + a1.z * r1 + skip.z;
        o.w = a0.w * r0 + a1.w * r1 + skip.w;
    } else {
        o = skip;
    }
    o.x = fmaxf(o.x, 0.f); o.y = fmaxf(o.y, 0.f);
    o.z = fmaxf(o.z, 0.f); o.w = fmaxf(o.w, 0.f);

    if (do_ln) {
        float mu = dpp_sum16(o.x + o.y + o.z + o.w) * (1.0f / 64.0f);
        float dx = o.x - mu, dy = o.y - mu, dz = o.z - mu, dw = o.w - mu;
        float var = dpp_sum16(dx * dx + dy * dy + dz * dz + dw * dw) * (1.0f / 64.0f);
        float rs = rsqrtf(var + LN_EPS);
        float4 gm = *(const float4*)&gamma[sub * 4];
        float4 bt = *(const float4*)&beta[sub * 4];
        o.x = dx * rs * gm.x + bt.x;
        o.y = dy * rs * gm.y + bt.y;
        o.z = dz * rs * gm.z + bt.z;
        o.w = dw * rs * gm.w + bt.w;
    }
    if (g == 0)
        *(float4*)&hout[(size_t)node * HIDDEN + sub * 4] = o;
}

// ---------------------------------------------------------------------------
// Pooling: batch is sorted; per-block register accumulation, rare atomic flush
// ---------------------------------------------------------------------------
#define POOL_NODES 256
__global__ __launch_bounds__(64) void pool_kernel(const float* __restrict__ h,
                                                  const int* __restrict__ batch,
                                                  float* __restrict__ pooled,
                                                  float* __restrict__ cnt, int N)
{
    int lane = threadIdx.x;
    int start = blockIdx.x * POOL_NODES;
    if (start >= N) return;
    int end = min(start + POOL_NODES, N);
    float acc = 0.f;
    int cur = batch[start];
    int c = 0;
    for (int i = start; i < end; ++i) {
        int b = batch[i];
        if (b != cur) {
            atomicAdd(&pooled[cur * HIDDEN + lane], acc);
            if (lane == 0) atomicAdd(&cnt[cur], (float)c);
            acc = 0.f; c = 0; cur = b;
        }
        acc += h[(size_t)i * HIDDEN + lane];
        ++c;
    }
    atomicAdd(&pooled[cur * HIDDEN + lane], acc);
    if (lane == 0) atomicAdd(&cnt[cur], (float)c);
}

__global__ void final_kernel(const float* __restrict__ pooled, const float* __restrict__ cnt,
                             const float* __restrict__ Wp, const float* __restrict__ bp,
                             float* __restrict__ out)
{
    int g = threadIdx.x;   // 64 graphs
    float c = fmaxf(cnt[g], 1.0f);
    float s = 0.f;
    for (int d = 0; d < HIDDEN; ++d) s += pooled[g * HIDDEN + d] * Wp[d];
    out[g] = s / c + bp[0];
}

// ---------------------------------------------------------------------------
// Host launcher
// ---------------------------------------------------------------------------
extern "C" void kernel_launch(void* const* d_in, const int* in_sizes, int n_in,
                              void* d_out, int out_size, void* d_ws, size_t ws_size,
                              hipStream_t stream)
{
    const float* x    = (const float*)d_in[0];
    const int*   ei   = (const int*)d_in[1];
    const int*   batch= (const int*)d_in[2];

    const float* Wl[3][4];  // Wq, Wk, Wv, Ws
    const float* bl[3][4];  // bq, bk, bv, bs
    for (int l = 0; l < 3; ++l) {
        int b = 3 + l * 8;
        Wl[l][0] = (const float*)d_in[b + 0]; bl[l][0] = (const float*)d_in[b + 1];
        Wl[l][1] = (const float*)d_in[b + 2]; bl[l][1] = (const float*)d_in[b + 3];
        Wl[l][2] = (const float*)d_in[b + 4]; bl[l][2] = (const float*)d_in[b + 5];
        Wl[l][3] = (const float*)d_in[b + 6]; bl[l][3] = (const float*)d_in[b + 7];
    }
    const float* g0    = (const float*)d_in[27];
    const float* beta0 = (const float*)d_in[28];
    const float* g1    = (const float*)d_in[29];
    const float* beta1 = (const float*)d_in[30];
    const float* Wp    = (const float*)d_in[31];
    const float* bp    = (const float*)d_in[32];

    const int N = in_sizes[0] / 128;   // 50000
    const int E = in_sizes[1] / 2;     // 800000

    // workspace carve (256B aligned)
    size_t off = 0;
    auto carve = [&](size_t bytes) -> char* {
        char* p = (char*)d_ws + off;
        off = (off + bytes + 255) & ~(size_t)255;
        return p;
    };
    float*  qs       = (float*)carve((size_t)N * QS_COLS * 4);
    float*  kv       = (float*)carve((size_t)N * KV_COLS * 4);
    float*  h        = (float*)carve((size_t)N * HIDDEN * 4);
    float*  Wcat     = (float*)carve(128 * NCOLS * 4);
    float*  bcat     = (float*)carve(NCOLS * 4);
    int*    counts   = (int*)carve((size_t)N * 4);
    int*    row_ptr  = (int*)carve((size_t)(N + 1) * 4);
    int*    cursor   = (int*)carve((size_t)N * 4);
    int*    src_sorted = (int*)carve((size_t)E * 4);
    int*    bsum     = (int*)carve(1024 * 4);
    int*    boff     = (int*)carve(1024 * 4);
    float*  pooled   = (float*)carve((size_t)(N_GRAPHS * HIDDEN + N_GRAPHS) * 4);
    float*  cntf     = pooled + N_GRAPHS * HIDDEN;

    const int nb = (N + 255) / 256;    // 196 scan blocks

    // ---- CSR build (dst is layer-invariant) ----
    hipMemsetAsync(counts, 0, (size_t)N * 4, stream);
    hist_kernel<<<(E + 255) / 256, 256, 0, stream>>>(ei + E, counts, E);
    block_reduce_kernel<<<nb, 256, 0, stream>>>(counts, bsum, N);
    scan_partials_kernel<<<1, 256, 0, stream>>>(bsum, boff, nb, &row_ptr[N]);
    block_scan_kernel<<<nb, 256, 0, stream>>>(counts, boff, row_ptr, cursor, N);
    scatter_kernel<<<(E + 255) / 256, 256, 0, stream>>>(ei, cursor, src_sorted, E);

    // ---- 3 TransformerConv layers ----
    for (int l = 0; l < 3; ++l) {
        int K = (l == 0) ? 128 : 64;
        const float* Ain = (l == 0) ? x : h;
        int packTot = K * NCOLS;
        pack_kernel<<<(packTot + 255) / 256, 256, 0, stream>>>(
            Wl[l][0], Wl[l][1], Wl[l][2], Wl[l][3],
            bl[l][0], bl[l][1], bl[l][2], bl[l][3], Wcat, bcat, K);
        if (l == 0) {
            dim3 ggrid(NCOLS / BN, (N + BM - 1) / BM);
            gemm_bias_kernel<<<ggrid, 256, 0, stream>>>(Ain, Wcat, bcat, qs, kv, N, K);
        } else {
            gemm_persistB_kernel<<<256, 512, 0, stream>>>(Ain, Wcat, bcat, qs, kv, N);
        }
        int do_ln = (l < 2) ? 1 : 0;
        const float* gg = (l == 0) ? g0 : g1;
        const float* bb = (l == 0) ? beta0 : beta1;
        edge_conv_kernel<<<(N + 3) / 4, 256, 0, stream>>>(
            qs, kv, row_ptr, src_sorted, gg, bb, h, N, do_ln);
    }

    // ---- global mean pool + head ----
    hipMemsetAsync(pooled, 0, (size_t)(N_GRAPHS * HIDDEN + N_GRAPHS) * 4, stream);
    pool_kernel<<<(N + POOL_NODES - 1) / POOL_NODES, 64, 0, stream>>>(h, batch, pooled, cntf, N);
    final_kernel<<<1, 64, 0, stream>>>(pooled, cntf, Wp, bp, (float*)d_out);
}

// Round 7
// 641.468 us; speedup vs baseline: 1.2892x; 1.2892x over previous
//
#include <hip/hip_runtime.h>
#include <hip/hip_fp16.h>
#include <math.h>

// ---------------------------------------------------------------------------
// Problem constants (from reference)
// ---------------------------------------------------------------------------
#define HIDDEN 64
#define HEADS 2
#define NCOLS 448          // GEMM logical cols: q(128) k(128) v(128) s(64)
#define QS_COLS 192        // fp32: q0 q1 (128) + skip (64)
#define KV_COLS 256        // fp16 halves: chunk-interleaved k/v
#define N_GRAPHS 64
#define LN_EPS 1e-5f

// kvh element index for head h, dim d, mat(0=k,1=v): mat*128 + (d>>2)*8 + h*4 + (d&3)

// ---------------------------------------------------------------------------
// Weight pack: Wcat[K][448] = [Wq*0.125 | Wk | Wv | Ws], bcat[448]
// ---------------------------------------------------------------------------
__global__ void pack_kernel(const float* __restrict__ Wq, const float* __restrict__ Wk,
                            const float* __restrict__ Wv, const float* __restrict__ Ws,
                            const float* __restrict__ bq, const float* __restrict__ bk,
                            const float* __restrict__ bv, const float* __restrict__ bs,
                            float* __restrict__ Wcat, float* __restrict__ bcat, int K)
{
    int idx = blockIdx.x * 256 + threadIdx.x;
    int total = K * NCOLS;
    if (idx < total) {
        int r = idx / NCOLS, c = idx - r * NCOLS;
        float v;
        if      (c < 128) v = Wq[r * 128 + c] * 0.125f;
        else if (c < 256) v = Wk[r * 128 + (c - 128)];
        else if (c < 384) v = Wv[r * 128 + (c - 256)];
        else              v = Ws[r * 64  + (c - 384)];
        Wcat[idx] = v;
    }
    if (idx < NCOLS) {
        float b;
        if      (idx < 128) b = bq[idx] * 0.125f;
        else if (idx < 256) b = bk[idx - 128];
        else if (idx < 384) b = bv[idx - 256];
        else                b = bs[idx - 384];
        bcat[idx] = b;
    }
}

// ---------------------------------------------------------------------------
// Shared epilogue: thread owns (row, lane) covering cols {lane + 64j}, j=0..6
//   j 0,1 -> qs q;  j 6 -> qs skip;  j 2..5 -> kvh (k0,k1,v0,v1) fp16
// ---------------------------------------------------------------------------
__device__ __forceinline__ void write_row_outputs(
    float* __restrict__ qs, __half* __restrict__ kvh,
    int row, int lane, const float* acc7, const float* bj)
{
    #pragma unroll
    for (int j = 0; j < 7; ++j) {
        float o = acc7[j] + bj[j];
        if (j < 2) {
            qs[(size_t)row * QS_COLS + lane + 64 * j] = o;
        } else if (j == 6) {
            qs[(size_t)row * QS_COLS + 128 + lane] = o;
        } else {
            int mat = (j - 2) >> 1;   // 0=k, 1=v
            int hh  = (j - 2) & 1;
            int pos = mat * 128 + (lane >> 2) * 8 + hh * 4 + (lane & 3);
            kvh[(size_t)row * KV_COLS + pos] = __float2half_rn(o);
        }
    }
}

// ---------------------------------------------------------------------------
// Layer-0 GEMM (K=128), persistB structure with two B-halves per chunk.
// LDS: Bs[64][448] (114.7KB) + As[64][128] (32KB) = 144KB -> 1 block/CU.
// A read from HBM exactly once; B (229KB) reloaded per chunk from hot L2.
// ---------------------------------------------------------------------------
__global__ __launch_bounds__(512) void gemm_persistB128_kernel(
    const float* __restrict__ A,     // [M][128]
    const float* __restrict__ B,     // [128][448] packed
    const float* __restrict__ bias,  // [448]
    float* __restrict__ qs, __half* __restrict__ kvh, int M)
{
    __shared__ float Bs[64][NCOLS];
    __shared__ float As[64][128];

    int t    = threadIdx.x;
    int lane = t & 63;
    int wv   = t >> 6;               // 0..7

    float bj[7];
    #pragma unroll
    for (int j = 0; j < 7; ++j) bj[j] = bias[lane + 64 * j];

    int nchunks = (M + 63) / 64;
    for (int c = blockIdx.x; c < nchunks; c += gridDim.x) {
        int row0 = c * 64;
        __syncthreads();   // previous chunk's reads done before restaging
        // stage A chunk [64][128]: 2048 float4, 4/thread, coalesced
        #pragma unroll
        for (int i = 0; i < 4; ++i) {
            int f  = t + i * 512;
            int r  = f >> 5;
            int c4 = f & 31;
            float4 v = make_float4(0.f, 0.f, 0.f, 0.f);
            if (row0 + r < M) v = *(const float4*)&A[(size_t)(row0 + r) * 128 + c4 * 4];
            *(float4*)&As[r][c4 * 4] = v;
        }
        // stage B half 0 (rows 0..63): 7168 float4, 14/thread
        for (int i = t; i < 64 * 112; i += 512) {
            int k  = i / 112;
            int c4 = i - k * 112;
            *(float4*)&Bs[k][c4 * 4] = *(const float4*)&B[(size_t)k * NCOLS + c4 * 4];
        }
        __syncthreads();

        float acc[8][7] = {};
        #pragma unroll 4
        for (int k = 0; k < 64; ++k) {
            float a[8];
            #pragma unroll
            for (int r = 0; r < 8; ++r) a[r] = As[wv * 8 + r][k];   // broadcast
            float b[7];
            #pragma unroll
            for (int j = 0; j < 7; ++j) b[j] = Bs[k][lane + 64 * j];
            #pragma unroll
            for (int r = 0; r < 8; ++r)
                #pragma unroll
                for (int j = 0; j < 7; ++j)
                    acc[r][j] = fmaf(a[r], b[j], acc[r][j]);
        }
        __syncthreads();
        // stage B half 1 (rows 64..127)
        for (int i = t; i < 64 * 112; i += 512) {
            int k  = i / 112;
            int c4 = i - k * 112;
            *(float4*)&Bs[k][c4 * 4] = *(const float4*)&B[(size_t)(64 + k) * NCOLS + c4 * 4];
        }
        __syncthreads();
        #pragma unroll 4
        for (int k = 0; k < 64; ++k) {
            float a[8];
            #pragma unroll
            for (int r = 0; r < 8; ++r) a[r] = As[wv * 8 + r][64 + k];
            float b[7];
            #pragma unroll
            for (int j = 0; j < 7; ++j) b[j] = Bs[k][lane + 64 * j];
            #pragma unroll
            for (int r = 0; r < 8; ++r)
                #pragma unroll
                for (int j = 0; j < 7; ++j)
                    acc[r][j] = fmaf(a[r], b[j], acc[r][j]);
        }

        #pragma unroll
        for (int r = 0; r < 8; ++r) {
            int row = row0 + wv * 8 + r;
            if (row < M) write_row_outputs(qs, kvh, row, lane, acc[r], bj);
        }
    }
}

// ---------------------------------------------------------------------------
// Layers 1-2 GEMM (K=64): entire B [64][448] persistent in LDS + 64-row
// A chunks. 512 threads; A/B each read from HBM exactly once.
// ---------------------------------------------------------------------------
__global__ __launch_bounds__(512) void gemm_persistB_kernel(
    const float* __restrict__ A,     // [M][64]
    const float* __restrict__ B,     // [64][448] packed
    const float* __restrict__ bias,  // [448]
    float* __restrict__ qs, __half* __restrict__ kvh, int M)
{
    __shared__ float Bs[64][NCOLS];  // 114,688 B
    __shared__ float As[64][64];     //  16,384 B

    int t    = threadIdx.x;
    int lane = t & 63;
    int wv   = t >> 6;

    for (int i = t; i < 64 * 112; i += 512) {
        int k  = i / 112;
        int c4 = i - k * 112;
        *(float4*)&Bs[k][c4 * 4] = *(const float4*)&B[(size_t)k * NCOLS + c4 * 4];
    }
    float bj[7];
    #pragma unroll
    for (int j = 0; j < 7; ++j) bj[j] = bias[lane + 64 * j];
    __syncthreads();

    int nchunks = (M + 63) / 64;
    for (int c = blockIdx.x; c < nchunks; c += gridDim.x) {
        int row0 = c * 64;
        #pragma unroll
        for (int i = 0; i < 2; ++i) {
            int f  = t + i * 512;
            int r  = f >> 4;
            int c4 = f & 15;
            float4 v = make_float4(0.f, 0.f, 0.f, 0.f);
            if (row0 + r < M) v = *(const float4*)&A[(size_t)(row0 + r) * 64 + c4 * 4];
            *(float4*)&As[r][c4 * 4] = v;
        }
        __syncthreads();

        float acc[8][7] = {};
        #pragma unroll 4
        for (int k = 0; k < 64; ++k) {
            float a[8];
            #pragma unroll
            for (int r = 0; r < 8; ++r) a[r] = As[wv * 8 + r][k];   // broadcast
            float b[7];
            #pragma unroll
            for (int j = 0; j < 7; ++j) b[j] = Bs[k][lane + 64 * j];
            #pragma unroll
            for (int r = 0; r < 8; ++r)
                #pragma unroll
                for (int j = 0; j < 7; ++j)
                    acc[r][j] = fmaf(a[r], b[j], acc[r][j]);
        }
        __syncthreads();   // before next chunk overwrites As

        #pragma unroll
        for (int r = 0; r < 8; ++r) {
            int row = row0 + wv * 8 + r;
            if (row < M) write_row_outputs(qs, kvh, row, lane, acc[r], bj);
        }
    }
}

// ---------------------------------------------------------------------------
// CSR build: histogram -> 3-kernel parallel scan -> scatter
// ---------------------------------------------------------------------------
__global__ void hist_kernel(const int* __restrict__ dst, int* __restrict__ counts, int E)
{
    int i = blockIdx.x * 256 + threadIdx.x;
    if (i < E) atomicAdd(&counts[dst[i]], 1);
}

__global__ __launch_bounds__(256) void block_reduce_kernel(
    const int* __restrict__ counts, int* __restrict__ bsum, int N)
{
    __shared__ int s[256];
    int t = threadIdx.x;
    int i = blockIdx.x * 256 + t;
    s[t] = (i < N) ? counts[i] : 0;
    __syncthreads();
    #pragma unroll
    for (int o = 128; o; o >>= 1) {
        if (t < o) s[t] += s[t + o];
        __syncthreads();
    }
    if (t == 0) bsum[blockIdx.x] = s[0];
}

__global__ __launch_bounds__(256) void scan_partials_kernel(
    const int* __restrict__ bsum, int* __restrict__ boff, int nb, int* __restrict__ rowN)
{
    __shared__ int s[256];
    int t = threadIdx.x;
    int v = (t < nb) ? bsum[t] : 0;
    s[t] = v;
    __syncthreads();
    #pragma unroll
    for (int o = 1; o < 256; o <<= 1) {
        int x = (t >= o) ? s[t - o] : 0;
        __syncthreads();
        s[t] += x;
        __syncthreads();
    }
    if (t < nb) boff[t] = s[t] - v;     // exclusive
    if (t == nb - 1) rowN[0] = s[t];    // total = row_ptr[N]
}

__global__ __launch_bounds__(256) void block_scan_kernel(
    const int* __restrict__ counts, const int* __restrict__ boff,
    int* __restrict__ row_ptr, int* __restrict__ cursor, int N)
{
    __shared__ int s[256];
    int t = threadIdx.x;
    int i = blockIdx.x * 256 + t;
    int v = (i < N) ? counts[i] : 0;
    s[t] = v;
    __syncthreads();
    #pragma unroll
    for (int o = 1; o < 256; o <<= 1) {
        int x = (t >= o) ? s[t - o] : 0;
        __syncthreads();
        s[t] += x;
        __syncthreads();
    }
    if (i < N) {
        int excl = s[t] - v + boff[blockIdx.x];
        row_ptr[i] = excl;
        cursor[i]  = excl;
    }
}

__global__ void scatter_kernel(const int* __restrict__ ei, int* __restrict__ cursor,
                               int* __restrict__ src_sorted, int E)
{
    int i = blockIdx.x * 256 + threadIdx.x;
    if (i < E) {
        int d = ei[E + i];                    // dst
        int pos = atomicAdd(&cursor[d], 1);
        src_sorted[pos] = ei[i];              // src
    }
}

// ---------------------------------------------------------------------------
// DPP 16-lane sum (pure VALU)
// ---------------------------------------------------------------------------
__device__ __forceinline__ float dpp_sum16(float x)
{
    float t;
    t = __int_as_float(__builtin_amdgcn_mov_dpp(__float_as_int(x), 0xB1,  0xF, 0xF, true)); x += t; // xor 1
    t = __int_as_float(__builtin_amdgcn_mov_dpp(__float_as_int(x), 0x4E,  0xF, 0xF, true)); x += t; // xor 2
    t = __int_as_float(__builtin_amdgcn_mov_dpp(__float_as_int(x), 0x141, 0xF, 0xF, true)); x += t; // half-mirror
    t = __int_as_float(__builtin_amdgcn_mov_dpp(__float_as_int(x), 0x140, 0xF, 0xF, true)); x += t; // row-mirror
    return x;
}

// ---------------------------------------------------------------------------
// Fused edge kernel: one wave per dst node, 4 edge-groups x 16 lanes.
// Direct src_sorted[e] index loads (NO shfl preload — R4/R5 bug).
// fp16 K/V gathers: 2 x uint4 per lane per edge (512B/edge total).
// Register double-buffer, DPP dot-reduce, flash merge, head-mean+skip+ReLU+LN.
// ---------------------------------------------------------------------------
__global__ __launch_bounds__(256) void edge_conv_kernel(
    const float* __restrict__ qs, const __half* __restrict__ kvh,
    const int* __restrict__ row_ptr, const int* __restrict__ src_sorted,
    const float* __restrict__ gamma, const float* __restrict__ beta,
    float* __restrict__ hout, int N, int do_ln)
{
    int wave = threadIdx.x >> 6;
    int lane = threadIdx.x & 63;
    int g    = lane >> 4;        // edge-group 0..3
    int sub  = lane & 15;        // dim-chunk 0..15 (4 dims each)
    int node = blockIdx.x * 4 + wave;
    if (node >= N) return;

    const float* qb = qs + (size_t)node * QS_COLS;
    float4 q0 = *(const float4*)&qb[sub * 4];        // pre-scaled by 1/8
    float4 q1 = *(const float4*)&qb[64 + sub * 4];

    int e0 = row_ptr[node], e1 = row_ptr[node + 1];
    int deg = e1 - e0;

    float  m0 = -1e30f, m1 = -1e30f;
    float  s0 = 0.f, s1 = 0.f;
    float4 a0 = make_float4(0.f, 0.f, 0.f, 0.f);
    float4 a1 = make_float4(0.f, 0.f, 0.f, 0.f);

    int  e    = e0 + g;
    bool have = (e < e1);
    uint4 kraw, vraw;
    if (have) {
        int j = src_sorted[e];
        const __half* jb = kvh + (size_t)j * KV_COLS;
        kraw = *(const uint4*)&jb[sub * 8];
        vraw = *(const uint4*)&jb[128 + sub * 8];
    }

    while (have) {
        int  en    = e + 4;
        bool haven = (en < e1);
        uint4 krn, vrn;
        if (haven) {
            int jn = src_sorted[en];
            const __half* jbn = kvh + (size_t)jn * KV_COLS;
            krn = *(const uint4*)&jbn[sub * 8];
            vrn = *(const uint4*)&jbn[128 + sub * 8];
        }

        // unpack current K: 8 halves = k0(4 dims) | k1(4 dims)
        const __half2* kp = (const __half2*)&kraw;
        float2 ka = __half22float2(kp[0]), kb = __half22float2(kp[1]);
        float2 kc = __half22float2(kp[2]), kd = __half22float2(kp[3]);

        float p0 = fmaf(q0.w, kb.y, fmaf(q0.z, kb.x, fmaf(q0.y, ka.y, q0.x * ka.x)));
        float p1 = fmaf(q1.w, kd.y, fmaf(q1.z, kd.x, fmaf(q1.y, kc.y, q1.x * kc.x)));
        float sc0 = dpp_sum16(p0);
        float sc1 = dpp_sum16(p1);

        const __half2* vp = (const __half2*)&vraw;
        float2 va = __half22float2(vp[0]), vb = __half22float2(vp[1]);
        float2 vc = __half22float2(vp[2]), vd = __half22float2(vp[3]);

        float nm0 = fmaxf(m0, sc0);
        float f0  = __expf(m0 - nm0);
        float w0  = __expf(sc0 - nm0);
        s0 = fmaf(s0, f0, w0);
        a0.x = fmaf(a0.x, f0, w0 * va.x);
        a0.y = fmaf(a0.y, f0, w0 * va.y);
        a0.z = fmaf(a0.z, f0, w0 * vb.x);
        a0.w = fmaf(a0.w, f0, w0 * vb.y);
        m0 = nm0;

        float nm1 = fmaxf(m1, sc1);
        float f1  = __expf(m1 - nm1);
        float w1  = __expf(sc1 - nm1);
        s1 = fmaf(s1, f1, w1);
        a1.x = fmaf(a1.x, f1, w1 * vc.x);
        a1.y = fmaf(a1.y, f1, w1 * vc.y);
        a1.z = fmaf(a1.z, f1, w1 * vd.x);
        a1.w = fmaf(a1.w, f1, w1 * vd.y);
        m1 = nm1;

        kraw = krn; vraw = vrn; e = en; have = haven;
    }

    // merge flash states across the 4 groups (xor 16, then 32)
    #pragma unroll
    for (int offm = 16; offm <= 32; offm <<= 1) {
        float mo0 = __shfl_xor(m0, offm);
        float so0 = __shfl_xor(s0, offm);
        float4 ao0;
        ao0.x = __shfl_xor(a0.x, offm); ao0.y = __shfl_xor(a0.y, offm);
        ao0.z = __shfl_xor(a0.z, offm); ao0.w = __shfl_xor(a0.w, offm);
        float nm = fmaxf(m0, mo0);
        float fa = __expf(m0 - nm), fb = __expf(mo0 - nm);
        s0 = s0 * fa + so0 * fb;
        a0.x = a0.x * fa + ao0.x * fb; a0.y = a0.y * fa + ao0.y * fb;
        a0.z = a0.z * fa + ao0.z * fb; a0.w = a0.w * fa + ao0.w * fb;
        m0 = nm;

        float mo1 = __shfl_xor(m1, offm);
        float so1 = __shfl_xor(s1, offm);
        float4 ao1;
        ao1.x = __shfl_xor(a1.x, offm); ao1.y = __shfl_xor(a1.y, offm);
        ao1.z = __shfl_xor(a1.z, offm); ao1.w = __shfl_xor(a1.w, offm);
        nm = fmaxf(m1, mo1);
        fa = __expf(m1 - nm); fb = __expf(mo1 - nm);
        s1 = s1 * fa + so1 * fb;
        a1.x = a1.x * fa + ao1.x * fb; a1.y = a1.y * fa + ao1.y * fb;
        a1.z = a1.z * fa + ao1.z * fb; a1.w = a1.w * fa + ao1.w * fb;
        m1 = nm;
    }

    float4 skip = *(const float4*)&qb[128 + sub * 4];
    float4 o;
    if (deg > 0) {
        float r0 = 0.5f / s0, r1 = 0.5f / s1;
        o.x = a0.x * r0 + a1.x * r1 + skip.x;
        o.y = a0.y * r0 + a1.y * r1 + skip.y;
        o.z = a0.z * r0 + a1.z * r1 + skip.z;
        o.w = a0.w * r0 + a1.w * r1 + skip.w;
    } else {
        o = skip;
    }
    o.x = fmaxf(o.x, 0.f); o.y = fmaxf(o.y, 0.f);
    o.z = fmaxf(o.z, 0.f); o.w = fmaxf(o.w, 0.f);

    if (do_ln) {
        float mu = dpp_sum16(o.x + o.y + o.z + o.w) * (1.0f / 64.0f);
        float dx = o.x - mu, dy = o.y - mu, dz = o.z - mu, dw = o.w - mu;
        float var = dpp_sum16(dx * dx + dy * dy + dz * dz + dw * dw) * (1.0f / 64.0f);
        float rs = rsqrtf(var + LN_EPS);
        float4 gm = *(const float4*)&gamma[sub * 4];
        float4 bt = *(const float4*)&beta[sub * 4];
        o.x = dx * rs * gm.x + bt.x;
        o.y = dy * rs * gm.y + bt.y;
        o.z = dz * rs * gm.z + bt.z;
        o.w = dw * rs * gm.w + bt.w;
    }
    if (g == 0)
        *(float4*)&hout[(size_t)node * HIDDEN + sub * 4] = o;
}

// ---------------------------------------------------------------------------
// Pooling: batch is sorted; per-block register accumulation, rare atomic flush
// ---------------------------------------------------------------------------
#define POOL_NODES 256
__global__ __launch_bounds__(64) void pool_kernel(const float* __restrict__ h,
                                                  const int* __restrict__ batch,
                                                  float* __restrict__ pooled,
                                                  float* __restrict__ cnt, int N)
{
    int lane = threadIdx.x;
    int start = blockIdx.x * POOL_NODES;
    if (start >= N) return;
    int end = min(start + POOL_NODES, N);
    float acc = 0.f;
    int cur = batch[start];
    int c = 0;
    for (int i = start; i < end; ++i) {
        int b = batch[i];
        if (b != cur) {
            atomicAdd(&pooled[cur * HIDDEN + lane], acc);
            if (lane == 0) atomicAdd(&cnt[cur], (float)c);
            acc = 0.f; c = 0; cur = b;
        }
        acc += h[(size_t)i * HIDDEN + lane];
        ++c;
    }
    atomicAdd(&pooled[cur * HIDDEN + lane], acc);
    if (lane == 0) atomicAdd(&cnt[cur], (float)c);
}

__global__ void final_kernel(const float* __restrict__ pooled, const float* __restrict__ cnt,
                             const float* __restrict__ Wp, const float* __restrict__ bp,
                             float* __restrict__ out)
{
    int g = threadIdx.x;   // 64 graphs
    float c = fmaxf(cnt[g], 1.0f);
    float s = 0.f;
    for (int d = 0; d < HIDDEN; ++d) s += pooled[g * HIDDEN + d] * Wp[d];
    out[g] = s / c + bp[0];
}

// ---------------------------------------------------------------------------
// Host launcher
// ---------------------------------------------------------------------------
extern "C" void kernel_launch(void* const* d_in, const int* in_sizes, int n_in,
                              void* d_out, int out_size, void* d_ws, size_t ws_size,
                              hipStream_t stream)
{
    const float* x    = (const float*)d_in[0];
    const int*   ei   = (const int*)d_in[1];
    const int*   batch= (const int*)d_in[2];

    const float* Wl[3][4];  // Wq, Wk, Wv, Ws
    const float* bl[3][4];  // bq, bk, bv, bs
    for (int l = 0; l < 3; ++l) {
        int b = 3 + l * 8;
        Wl[l][0] = (const float*)d_in[b + 0]; bl[l][0] = (const float*)d_in[b + 1];
        Wl[l][1] = (const float*)d_in[b + 2]; bl[l][1] = (const float*)d_in[b + 3];
        Wl[l][2] = (const float*)d_in[b + 4]; bl[l][2] = (const float*)d_in[b + 5];
        Wl[l][3] = (const float*)d_in[b + 6]; bl[l][3] = (const float*)d_in[b + 7];
    }
    const float* g0    = (const float*)d_in[27];
    const float* beta0 = (const float*)d_in[28];
    const float* g1    = (const float*)d_in[29];
    const float* beta1 = (const float*)d_in[30];
    const float* Wp    = (const float*)d_in[31];
    const float* bp    = (const float*)d_in[32];

    const int N = in_sizes[0] / 128;   // 50000
    const int E = in_sizes[1] / 2;     // 800000

    // workspace carve (256B aligned)
    size_t off = 0;
    auto carve = [&](size_t bytes) -> char* {
        char* p = (char*)d_ws + off;
        off = (off + bytes + 255) & ~(size_t)255;
        return p;
    };
    float*  qs       = (float*)carve((size_t)N * QS_COLS * 4);
    __half* kvh      = (__half*)carve((size_t)N * KV_COLS * 2);
    float*  h        = (float*)carve((size_t)N * HIDDEN * 4);
    float*  Wcat     = (float*)carve(128 * NCOLS * 4);
    float*  bcat     = (float*)carve(NCOLS * 4);
    int*    counts   = (int*)carve((size_t)N * 4);
    int*    row_ptr  = (int*)carve((size_t)(N + 1) * 4);
    int*    cursor   = (int*)carve((size_t)N * 4);
    int*    src_sorted = (int*)carve((size_t)E * 4);
    int*    bsum     = (int*)carve(1024 * 4);
    int*    boff     = (int*)carve(1024 * 4);
    float*  pooled   = (float*)carve((size_t)(N_GRAPHS * HIDDEN + N_GRAPHS) * 4);
    float*  cntf     = pooled + N_GRAPHS * HIDDEN;

    const int nb = (N + 255) / 256;    // 196 scan blocks

    // ---- CSR build (dst is layer-invariant) ----
    hipMemsetAsync(counts, 0, (size_t)N * 4, stream);
    hist_kernel<<<(E + 255) / 256, 256, 0, stream>>>(ei + E, counts, E);
    block_reduce_kernel<<<nb, 256, 0, stream>>>(counts, bsum, N);
    scan_partials_kernel<<<1, 256, 0, stream>>>(bsum, boff, nb, &row_ptr[N]);
    block_scan_kernel<<<nb, 256, 0, stream>>>(counts, boff, row_ptr, cursor, N);
    scatter_kernel<<<(E + 255) / 256, 256, 0, stream>>>(ei, cursor, src_sorted, E);

    // ---- 3 TransformerConv layers ----
    for (int l = 0; l < 3; ++l) {
        int K = (l == 0) ? 128 : 64;
        const float* Ain = (l == 0) ? x : h;
        int packTot = K * NCOLS;
        pack_kernel<<<(packTot + 255) / 256, 256, 0, stream>>>(
            Wl[l][0], Wl[l][1], Wl[l][2], Wl[l][3],
            bl[l][0], bl[l][1], bl[l][2], bl[l][3], Wcat, bcat, K);
        if (l == 0) {
            gemm_persistB128_kernel<<<256, 512, 0, stream>>>(Ain, Wcat, bcat, qs, kvh, N);
        } else {
            gemm_persistB_kernel<<<256, 512, 0, stream>>>(Ain, Wcat, bcat, qs, kvh, N);
        }
        int do_ln = (l < 2) ? 1 : 0;
        const float* gg = (l == 0) ? g0 : g1;
        const float* bb = (l == 0) ? beta0 : beta1;
        edge_conv_kernel<<<(N + 3) / 4, 256, 0, stream>>>(
            qs, kvh, row_ptr, src_sorted, gg, bb, h, N, do_ln);
    }

    // ---- global mean pool + head ----
    hipMemsetAsync(pooled, 0, (size_t)(N_GRAPHS * HIDDEN + N_GRAPHS) * 4, stream);
    pool_kernel<<<(N + POOL_NODES - 1) / POOL_NODES, 64, 0, stream>>>(h, batch, pooled, cntf, N);
    final_kernel<<<1, 64, 0, stream>>>(pooled, cntf, Wp, bp, (float*)d_out);
}

// Round 8
// 577.629 us; speedup vs baseline: 1.4317x; 1.1105x over previous
//
#include <hip/hip_runtime.h>
#include <hip/hip_fp16.h>
#include <math.h>

// ---------------------------------------------------------------------------
// Problem constants (from reference)
// ---------------------------------------------------------------------------
#define HIDDEN 64
#define HEADS 2
#define NCOLS 448          // GEMM logical cols: q(128) k(128) v(128) s(64)
#define QS_COLS 192        // fp32: q0 q1 (128) + skip (64)
#define KV_COLS 256        // fp16 halves: chunk-interleaved k/v
#define N_GRAPHS 64
#define LN_EPS 1e-5f

typedef _Float16 half8 __attribute__((ext_vector_type(8)));
typedef float    f32x4 __attribute__((ext_vector_type(4)));

// kvh element index for head h, dim d, mat(0=k,1=v): mat*128 + (d>>2)*8 + h*4 + (d&3)

// ---------------------------------------------------------------------------
// Cast fp32 -> fp16, vectorized (n multiple of 4)
// ---------------------------------------------------------------------------
__global__ void cast_f2h_kernel(const float* __restrict__ in, _Float16* __restrict__ out, int n4)
{
    int i = blockIdx.x * 256 + threadIdx.x;
    if (i < n4) {
        float4 v = *(const float4*)&in[i * 4];
        __half2 a = __floats2half2_rn(v.x, v.y);
        __half2 b = __floats2half2_rn(v.z, v.w);
        uint2 pk;
        pk.x = *(unsigned int*)&a;
        pk.y = *(unsigned int*)&b;
        *(uint2*)&out[i * 4] = pk;
    }
}

// ---------------------------------------------------------------------------
// Weight pack (transposed, fp16): Bt[448][K], Bt[c][k] = W[k][c] (q scaled
// by 0.125 — exact pow2). bcat[448] fp32.
// ---------------------------------------------------------------------------
__global__ void pack_kernel(const float* __restrict__ Wq, const float* __restrict__ Wk,
                            const float* __restrict__ Wv, const float* __restrict__ Ws,
                            const float* __restrict__ bq, const float* __restrict__ bk,
                            const float* __restrict__ bv, const float* __restrict__ bs,
                            _Float16* __restrict__ Bt, float* __restrict__ bcat, int K)
{
    int idx = blockIdx.x * 256 + threadIdx.x;
    int total = NCOLS * K;
    if (idx < total) {
        int c = idx / K, k = idx - c * K;
        float v;
        if      (c < 128) v = Wq[k * 128 + c] * 0.125f;
        else if (c < 256) v = Wk[k * 128 + (c - 128)];
        else if (c < 384) v = Wv[k * 128 + (c - 256)];
        else              v = Ws[k * 64  + (c - 384)];
        Bt[idx] = (_Float16)v;
    }
    if (idx < NCOLS) {
        float b;
        if      (idx < 128) b = bq[idx] * 0.125f;
        else if (idx < 256) b = bk[idx - 128];
        else if (idx < 384) b = bv[idx - 256];
        else                b = bs[idx - 384];
        bcat[idx] = b;
    }
}

// ---------------------------------------------------------------------------
// MFMA GEMM: C[M,448] = Ah[M,K]fp16 @ W + bias, fp32 accum.
// 256 threads = 4 waves; block = 64 rows x 448 cols; wave = 16 rows.
// 28 col-tiles/wave, 16x16x32 f16 MFMA, K/32 k-steps. No LDS, no barriers:
// A-frag = one 16B global load/lane (row = lane&15, k = (lane>>4)*8+j);
// B-frag from transposed Bt (col = lane&15) — m92-verified B^T pattern.
// C/D: row=(lane>>4)*4+reg, col=lane&15 (m89-verified, dtype-independent).
// Split epilogue: q/skip -> qs fp32, k/v -> kvh fp16 chunk-interleaved.
// ---------------------------------------------------------------------------
template<int K>
__global__ __launch_bounds__(256) void gemm_mfma_kernel(
    const _Float16* __restrict__ Ah,   // [M][K]
    const _Float16* __restrict__ Bt,   // [448][K]
    const float* __restrict__ bias,    // [448]
    float* __restrict__ qs, __half* __restrict__ kvh, int M)
{
    int lane = threadIdx.x & 63;
    int w    = threadIdx.x >> 6;           // 0..3
    int row0 = blockIdx.x * 64 + w * 16;   // wave's 16-row strip
    int fr   = lane & 15;
    int g    = lane >> 4;

    int arow = row0 + fr;
    if (arow > M - 1) arow = M - 1;        // clamp (stores guarded)

    f32x4 acc[28];
    #pragma unroll
    for (int c = 0; c < 28; ++c) acc[c] = (f32x4){0.f, 0.f, 0.f, 0.f};

    #pragma unroll
    for (int ks = 0; ks < K / 32; ++ks) {
        int k0 = ks * 32 + g * 8;
        half8 af = *(const half8*)&Ah[(size_t)arow * K + k0];
        #pragma unroll
        for (int c = 0; c < 28; ++c) {
            half8 bf = *(const half8*)&Bt[(size_t)(c * 16 + fr) * K + k0];
            acc[c] = __builtin_amdgcn_mfma_f32_16x16x32_f16(af, bf, acc[c], 0, 0, 0);
        }
    }

    #pragma unroll
    for (int c = 0; c < 28; ++c) {
        int col = c * 16 + fr;
        float bs = bias[col];
        #pragma unroll
        for (int j = 0; j < 4; ++j) {
            int row = row0 + g * 4 + j;
            if (row >= M) continue;
            float o = acc[c][j] + bs;
            if (col < 128) {
                qs[(size_t)row * QS_COLS + col] = o;
            } else if (col >= 384) {
                qs[(size_t)row * QS_COLS + 128 + (col - 384)] = o;
            } else {
                int cc  = col - 128;
                int mat = cc >> 7;          // 0=k, 1=v
                int hh  = (cc >> 6) & 1;
                int d   = cc & 63;
                int pos = mat * 128 + (d >> 2) * 8 + hh * 4 + (d & 3);
                kvh[(size_t)row * KV_COLS + pos] = __float2half_rn(o);
            }
        }
    }
}

// ---------------------------------------------------------------------------
// CSR build: histogram -> 3-kernel parallel scan -> scatter
// ---------------------------------------------------------------------------
__global__ void hist_kernel(const int* __restrict__ dst, int* __restrict__ counts, int E)
{
    int i = blockIdx.x * 256 + threadIdx.x;
    if (i < E) atomicAdd(&counts[dst[i]], 1);
}

__global__ __launch_bounds__(256) void block_reduce_kernel(
    const int* __restrict__ counts, int* __restrict__ bsum, int N)
{
    __shared__ int s[256];
    int t = threadIdx.x;
    int i = blockIdx.x * 256 + t;
    s[t] = (i < N) ? counts[i] : 0;
    __syncthreads();
    #pragma unroll
    for (int o = 128; o; o >>= 1) {
        if (t < o) s[t] += s[t + o];
        __syncthreads();
    }
    if (t == 0) bsum[blockIdx.x] = s[0];
}

__global__ __launch_bounds__(256) void scan_partials_kernel(
    const int* __restrict__ bsum, int* __restrict__ boff, int nb, int* __restrict__ rowN)
{
    __shared__ int s[256];
    int t = threadIdx.x;
    int v = (t < nb) ? bsum[t] : 0;
    s[t] = v;
    __syncthreads();
    #pragma unroll
    for (int o = 1; o < 256; o <<= 1) {
        int x = (t >= o) ? s[t - o] : 0;
        __syncthreads();
        s[t] += x;
        __syncthreads();
    }
    if (t < nb) boff[t] = s[t] - v;     // exclusive
    if (t == nb - 1) rowN[0] = s[t];    // total = row_ptr[N]
}

__global__ __launch_bounds__(256) void block_scan_kernel(
    const int* __restrict__ counts, const int* __restrict__ boff,
    int* __restrict__ row_ptr, int* __restrict__ cursor, int N)
{
    __shared__ int s[256];
    int t = threadIdx.x;
    int i = blockIdx.x * 256 + t;
    int v = (i < N) ? counts[i] : 0;
    s[t] = v;
    __syncthreads();
    #pragma unroll
    for (int o = 1; o < 256; o <<= 1) {
        int x = (t >= o) ? s[t - o] : 0;
        __syncthreads();
        s[t] += x;
        __syncthreads();
    }
    if (i < N) {
        int excl = s[t] - v + boff[blockIdx.x];
        row_ptr[i] = excl;
        cursor[i]  = excl;
    }
}

__global__ void scatter_kernel(const int* __restrict__ ei, int* __restrict__ cursor,
                               int* __restrict__ src_sorted, int E)
{
    int i = blockIdx.x * 256 + threadIdx.x;
    if (i < E) {
        int d = ei[E + i];                    // dst
        int pos = atomicAdd(&cursor[d], 1);
        src_sorted[pos] = ei[i];              // src
    }
}

// ---------------------------------------------------------------------------
// DPP 16-lane sum (pure VALU)
// ---------------------------------------------------------------------------
__device__ __forceinline__ float dpp_sum16(float x)
{
    float t;
    t = __int_as_float(__builtin_amdgcn_mov_dpp(__float_as_int(x), 0xB1,  0xF, 0xF, true)); x += t; // xor 1
    t = __int_as_float(__builtin_amdgcn_mov_dpp(__float_as_int(x), 0x4E,  0xF, 0xF, true)); x += t; // xor 2
    t = __int_as_float(__builtin_amdgcn_mov_dpp(__float_as_int(x), 0x141, 0xF, 0xF, true)); x += t; // half-mirror
    t = __int_as_float(__builtin_amdgcn_mov_dpp(__float_as_int(x), 0x140, 0xF, 0xF, true)); x += t; // row-mirror
    return x;
}

// ---------------------------------------------------------------------------
// Fused edge kernel: one wave per dst node, 4 edge-groups x 16 lanes.
// Direct src_sorted[e] index loads (NO shfl preload — R4/R5 bug).
// fp16 K/V gathers: 2 x uint4 per lane per edge. Register double-buffer,
// DPP dot-reduce, flash merge, head-mean+skip+ReLU+LN.
// Writes h fp32 (pool) AND hh fp16 (next layer's GEMM A).
// ---------------------------------------------------------------------------
__global__ __launch_bounds__(256) void edge_conv_kernel(
    const float* __restrict__ qs, const __half* __restrict__ kvh,
    const int* __restrict__ row_ptr, const int* __restrict__ src_sorted,
    const float* __restrict__ gamma, const float* __restrict__ beta,
    float* __restrict__ hout, _Float16* __restrict__ hh, int N, int do_ln)
{
    int wave = threadIdx.x >> 6;
    int lane = threadIdx.x & 63;
    int g    = lane >> 4;        // edge-group 0..3
    int sub  = lane & 15;        // dim-chunk 0..15 (4 dims each)
    int node = blockIdx.x * 4 + wave;
    if (node >= N) return;

    const float* qb = qs + (size_t)node * QS_COLS;
    float4 q0 = *(const float4*)&qb[sub * 4];        // pre-scaled by 1/8
    float4 q1 = *(const float4*)&qb[64 + sub * 4];

    int e0 = row_ptr[node], e1 = row_ptr[node + 1];
    int deg = e1 - e0;

    float  m0 = -1e30f, m1 = -1e30f;
    float  s0 = 0.f, s1 = 0.f;
    float4 a0 = make_float4(0.f, 0.f, 0.f, 0.f);
    float4 a1 = make_float4(0.f, 0.f, 0.f, 0.f);

    int  e    = e0 + g;
    bool have = (e < e1);
    uint4 kraw, vraw;
    if (have) {
        int j = src_sorted[e];
        const __half* jb = kvh + (size_t)j * KV_COLS;
        kraw = *(const uint4*)&jb[sub * 8];
        vraw = *(const uint4*)&jb[128 + sub * 8];
    }

    while (have) {
        int  en    = e + 4;
        bool haven = (en < e1);
        uint4 krn, vrn;
        if (haven) {
            int jn = src_sorted[en];
            const __half* jbn = kvh + (size_t)jn * KV_COLS;
            krn = *(const uint4*)&jbn[sub * 8];
            vrn = *(const uint4*)&jbn[128 + sub * 8];
        }

        // unpack current K: 8 halves = k0(4 dims) | k1(4 dims)
        const __half2* kp = (const __half2*)&kraw;
        float2 ka = __half22float2(kp[0]), kb = __half22float2(kp[1]);
        float2 kc = __half22float2(kp[2]), kd = __half22float2(kp[3]);

        float p0 = fmaf(q0.w, kb.y, fmaf(q0.z, kb.x, fmaf(q0.y, ka.y, q0.x * ka.x)));
        float p1 = fmaf(q1.w, kd.y, fmaf(q1.z, kd.x, fmaf(q1.y, kc.y, q1.x * kc.x)));
        float sc0 = dpp_sum16(p0);
        float sc1 = dpp_sum16(p1);

        const __half2* vp = (const __half2*)&vraw;
        float2 va = __half22float2(vp[0]), vb = __half22float2(vp[1]);
        float2 vc = __half22float2(vp[2]), vd = __half22float2(vp[3]);

        float nm0 = fmaxf(m0, sc0);
        float f0  = __expf(m0 - nm0);
        float w0  = __expf(sc0 - nm0);
        s0 = fmaf(s0, f0, w0);
        a0.x = fmaf(a0.x, f0, w0 * va.x);
        a0.y = fmaf(a0.y, f0, w0 * va.y);
        a0.z = fmaf(a0.z, f0, w0 * vb.x);
        a0.w = fmaf(a0.w, f0, w0 * vb.y);
        m0 = nm0;

        float nm1 = fmaxf(m1, sc1);
        float f1  = __expf(m1 - nm1);
        float w1  = __expf(sc1 - nm1);
        s1 = fmaf(s1, f1, w1);
        a1.x = fmaf(a1.x, f1, w1 * vc.x);
        a1.y = fmaf(a1.y, f1, w1 * vc.y);
        a1.z = fmaf(a1.z, f1, w1 * vd.x);
        a1.w = fmaf(a1.w, f1, w1 * vd.y);
        m1 = nm1;

        kraw = krn; vraw = vrn; e = en; have = haven;
    }

    // merge flash states across the 4 groups (xor 16, then 32)
    #pragma unroll
    for (int offm = 16; offm <= 32; offm <<= 1) {
        float mo0 = __shfl_xor(m0, offm);
        float so0 = __shfl_xor(s0, offm);
        float4 ao0;
        ao0.x = __shfl_xor(a0.x, offm); ao0.y = __shfl_xor(a0.y, offm);
        ao0.z = __shfl_xor(a0.z, offm); ao0.w = __shfl_xor(a0.w, offm);
        float nm = fmaxf(m0, mo0);
        float fa = __expf(m0 - nm), fb = __expf(mo0 - nm);
        s0 = s0 * fa + so0 * fb;
        a0.x = a0.x * fa + ao0.x * fb; a0.y = a0.y * fa + ao0.y * fb;
        a0.z = a0.z * fa + ao0.z * fb; a0.w = a0.w * fa + ao0.w * fb;
        m0 = nm;

        float mo1 = __shfl_xor(m1, offm);
        float so1 = __shfl_xor(s1, offm);
        float4 ao1;
        ao1.x = __shfl_xor(a1.x, offm); ao1.y = __shfl_xor(a1.y, offm);
        ao1.z = __shfl_xor(a1.z, offm); ao1.w = __shfl_xor(a1.w, offm);
        nm = fmaxf(m1, mo1);
        fa = __expf(m1 - nm); fb = __expf(mo1 - nm);
        s1 = s1 * fa + so1 * fb;
        a1.x = a1.x * fa + ao1.x * fb; a1.y = a1.y * fa + ao1.y * fb;
        a1.z = a1.z * fa + ao1.z * fb; a1.w = a1.w * fa + ao1.w * fb;
        m1 = nm;
    }

    float4 skip = *(const float4*)&qb[128 + sub * 4];
    float4 o;
    if (deg > 0) {
        float r0 = 0.5f / s0, r1 = 0.5f / s1;
        o.x = a0.x * r0 + a1.x * r1 + skip.x;
        o.y = a0.y * r0 + a1.y * r1 + skip.y;
        o.z = a0.z * r0 + a1.z * r1 + skip.z;
        o.w = a0.w * r0 + a1.w * r1 + skip.w;
    } else {
        o = skip;
    }
    o.x = fmaxf(o.x, 0.f); o.y = fmaxf(o.y, 0.f);
    o.z = fmaxf(o.z, 0.f); o.w = fmaxf(o.w, 0.f);

    if (do_ln) {
        float mu = dpp_sum16(o.x + o.y + o.z + o.w) * (1.0f / 64.0f);
        float dx = o.x - mu, dy = o.y - mu, dz = o.z - mu, dw = o.w - mu;
        float var = dpp_sum16(dx * dx + dy * dy + dz * dz + dw * dw) * (1.0f / 64.0f);
        float rs = rsqrtf(var + LN_EPS);
        float4 gm = *(const float4*)&gamma[sub * 4];
        float4 bt = *(const float4*)&beta[sub * 4];
        o.x = dx * rs * gm.x + bt.x;
        o.y = dy * rs * gm.y + bt.y;
        o.z = dz * rs * gm.z + bt.z;
        o.w = dw * rs * gm.w + bt.w;
    }
    if (g == 0) {
        *(float4*)&hout[(size_t)node * HIDDEN + sub * 4] = o;
        __half2 h01 = __floats2half2_rn(o.x, o.y);
        __half2 h23 = __floats2half2_rn(o.z, o.w);
        uint2 pk;
        pk.x = *(unsigned int*)&h01;
        pk.y = *(unsigned int*)&h23;
        *(uint2*)&hh[(size_t)node * HIDDEN + sub * 4] = pk;
    }
}

// ---------------------------------------------------------------------------
// Pooling: batch is sorted; per-block register accumulation, rare atomic flush
// ---------------------------------------------------------------------------
#define POOL_NODES 256
__global__ __launch_bounds__(64) void pool_kernel(const float* __restrict__ h,
                                                  const int* __restrict__ batch,
                                                  float* __restrict__ pooled,
                                                  float* __restrict__ cnt, int N)
{
    int lane = threadIdx.x;
    int start = blockIdx.x * POOL_NODES;
    if (start >= N) return;
    int end = min(start + POOL_NODES, N);
    float acc = 0.f;
    int cur = batch[start];
    int c = 0;
    for (int i = start; i < end; ++i) {
        int b = batch[i];
        if (b != cur) {
            atomicAdd(&pooled[cur * HIDDEN + lane], acc);
            if (lane == 0) atomicAdd(&cnt[cur], (float)c);
            acc = 0.f; c = 0; cur = b;
        }
        acc += h[(size_t)i * HIDDEN + lane];
        ++c;
    }
    atomicAdd(&pooled[cur * HIDDEN + lane], acc);
    if (lane == 0) atomicAdd(&cnt[cur], (float)c);
}

__global__ void final_kernel(const float* __restrict__ pooled, const float* __restrict__ cnt,
                             const float* __restrict__ Wp, const float* __restrict__ bp,
                             float* __restrict__ out)
{
    int g = threadIdx.x;   // 64 graphs
    float c = fmaxf(cnt[g], 1.0f);
    float s = 0.f;
    for (int d = 0; d < HIDDEN; ++d) s += pooled[g * HIDDEN + d] * Wp[d];
    out[g] = s / c + bp[0];
}

// ---------------------------------------------------------------------------
// Host launcher
// ---------------------------------------------------------------------------
extern "C" void kernel_launch(void* const* d_in, const int* in_sizes, int n_in,
                              void* d_out, int out_size, void* d_ws, size_t ws_size,
                              hipStream_t stream)
{
    const float* x    = (const float*)d_in[0];
    const int*   ei   = (const int*)d_in[1];
    const int*   batch= (const int*)d_in[2];

    const float* Wl[3][4];  // Wq, Wk, Wv, Ws
    const float* bl[3][4];  // bq, bk, bv, bs
    for (int l = 0; l < 3; ++l) {
        int b = 3 + l * 8;
        Wl[l][0] = (const float*)d_in[b + 0]; bl[l][0] = (const float*)d_in[b + 1];
        Wl[l][1] = (const float*)d_in[b + 2]; bl[l][1] = (const float*)d_in[b + 3];
        Wl[l][2] = (const float*)d_in[b + 4]; bl[l][2] = (const float*)d_in[b + 5];
        Wl[l][3] = (const float*)d_in[b + 6]; bl[l][3] = (const float*)d_in[b + 7];
    }
    const float* g0    = (const float*)d_in[27];
    const float* beta0 = (const float*)d_in[28];
    const float* g1    = (const float*)d_in[29];
    const float* beta1 = (const float*)d_in[30];
    const float* Wp    = (const float*)d_in[31];
    const float* bp    = (const float*)d_in[32];

    const int N = in_sizes[0] / 128;   // 50000
    const int E = in_sizes[1] / 2;     // 800000

    // workspace carve (256B aligned)
    size_t off = 0;
    auto carve = [&](size_t bytes) -> char* {
        char* p = (char*)d_ws + off;
        off = (off + bytes + 255) & ~(size_t)255;
        return p;
    };
    float*     qs     = (float*)carve((size_t)N * QS_COLS * 4);
    __half*    kvh    = (__half*)carve((size_t)N * KV_COLS * 2);
    float*     h      = (float*)carve((size_t)N * HIDDEN * 4);
    _Float16*  hh     = (_Float16*)carve((size_t)N * HIDDEN * 2);
    _Float16*  xh     = (_Float16*)carve((size_t)N * 128 * 2);
    _Float16*  Bt     = (_Float16*)carve((size_t)NCOLS * 128 * 2);
    float*     bcat   = (float*)carve(NCOLS * 4);
    int*       counts = (int*)carve((size_t)N * 4);
    int*       row_ptr= (int*)carve((size_t)(N + 1) * 4);
    int*       cursor = (int*)carve((size_t)N * 4);
    int*       src_sorted = (int*)carve((size_t)E * 4);
    int*       bsum   = (int*)carve(1024 * 4);
    int*       boff   = (int*)carve(1024 * 4);
    float*     pooled = (float*)carve((size_t)(N_GRAPHS * HIDDEN + N_GRAPHS) * 4);
    float*     cntf   = pooled + N_GRAPHS * HIDDEN;

    const int nb = (N + 255) / 256;    // 196 scan blocks

    // ---- CSR build (dst is layer-invariant) ----
    hipMemsetAsync(counts, 0, (size_t)N * 4, stream);
    hist_kernel<<<(E + 255) / 256, 256, 0, stream>>>(ei + E, counts, E);
    block_reduce_kernel<<<nb, 256, 0, stream>>>(counts, bsum, N);
    scan_partials_kernel<<<1, 256, 0, stream>>>(bsum, boff, nb, &row_ptr[N]);
    block_scan_kernel<<<nb, 256, 0, stream>>>(counts, boff, row_ptr, cursor, N);
    scatter_kernel<<<(E + 255) / 256, 256, 0, stream>>>(ei, cursor, src_sorted, E);

    // ---- cast x to fp16 once ----
    {
        int n4 = (N * 128) / 4;
        cast_f2h_kernel<<<(n4 + 255) / 256, 256, 0, stream>>>(x, xh, n4);
    }

    const int gemm_grid = (N + 63) / 64;   // 782 blocks

    // ---- 3 TransformerConv layers ----
    for (int l = 0; l < 3; ++l) {
        int K = (l == 0) ? 128 : 64;
        int packTot = NCOLS * K;
        pack_kernel<<<(packTot + 255) / 256, 256, 0, stream>>>(
            Wl[l][0], Wl[l][1], Wl[l][2], Wl[l][3],
            bl[l][0], bl[l][1], bl[l][2], bl[l][3], Bt, bcat, K);
        if (l == 0)
            gemm_mfma_kernel<128><<<gemm_grid, 256, 0, stream>>>(xh, Bt, bcat, qs, kvh, N);
        else
            gemm_mfma_kernel<64><<<gemm_grid, 256, 0, stream>>>(hh, Bt, bcat, qs, kvh, N);
        int do_ln = (l < 2) ? 1 : 0;
        const float* gg = (l == 0) ? g0 : g1;
        const float* bb = (l == 0) ? beta0 : beta1;
        edge_conv_kernel<<<(N + 3) / 4, 256, 0, stream>>>(
            qs, kvh, row_ptr, src_sorted, gg, bb, h, hh, N, do_ln);
    }

    // ---- global mean pool + head ----
    hipMemsetAsync(pooled, 0, (size_t)(N_GRAPHS * HIDDEN + N_GRAPHS) * 4, stream);
    pool_kernel<<<(N + POOL_NODES - 1) / POOL_NODES, 64, 0, stream>>>(h, batch, pooled, cntf, N);
    final_kernel<<<1, 64, 0, stream>>>(pooled, cntf, Wp, bp, (float*)d_out);
}

// Round 9
// 486.326 us; speedup vs baseline: 1.7004x; 1.1877x over previous
//
#include <hip/hip_runtime.h>
#include <hip/hip_fp16.h>
#include <math.h>

// ---------------------------------------------------------------------------
// Problem constants (from reference)
// ---------------------------------------------------------------------------
#define HIDDEN 64
#define HEADS 2
#define NCOLS 448          // GEMM logical cols: q(128) k(128) v(128) s(64)
#define QS_COLS 192        // fp32: q0 q1 (128) + skip (64)
#define KV_COLS 256        // fp16 halves: chunk-interleaved k/v
#define N_GRAPHS 64
#define LN_EPS 1e-5f

typedef _Float16 half8 __attribute__((ext_vector_type(8)));
typedef float    f32x4 __attribute__((ext_vector_type(4)));

// kvh element index for head h, dim d, mat(0=k,1=v): mat*128 + (d>>2)*8 + h*4 + (d&3)

// ---------------------------------------------------------------------------
// Cast fp32 -> fp16, vectorized (n multiple of 4)
// ---------------------------------------------------------------------------
__global__ void cast_f2h_kernel(const float* __restrict__ in, _Float16* __restrict__ out, int n4)
{
    int i = blockIdx.x * 256 + threadIdx.x;
    if (i < n4) {
        float4 v = *(const float4*)&in[i * 4];
        __half2 a = __floats2half2_rn(v.x, v.y);
        __half2 b = __floats2half2_rn(v.z, v.w);
        uint2 pk;
        pk.x = *(unsigned int*)&a;
        pk.y = *(unsigned int*)&b;
        *(uint2*)&out[i * 4] = pk;
    }
}

// ---------------------------------------------------------------------------
// Weight pack (transposed, fp16): Bt[448][K], Bt[c][k] = W[k][c] (q scaled
// by 0.125 — exact pow2). bcat[448] fp32.
// ---------------------------------------------------------------------------
__global__ void pack_kernel(const float* __restrict__ Wq, const float* __restrict__ Wk,
                            const float* __restrict__ Wv, const float* __restrict__ Ws,
                            const float* __restrict__ bq, const float* __restrict__ bk,
                            const float* __restrict__ bv, const float* __restrict__ bs,
                            _Float16* __restrict__ Bt, float* __restrict__ bcat, int K)
{
    int idx = blockIdx.x * 256 + threadIdx.x;
    int total = NCOLS * K;
    if (idx < total) {
        int c = idx / K, k = idx - c * K;
        float v;
        if      (c < 128) v = Wq[k * 128 + c] * 0.125f;
        else if (c < 256) v = Wk[k * 128 + (c - 128)];
        else if (c < 384) v = Wv[k * 128 + (c - 256)];
        else              v = Ws[k * 64  + (c - 384)];
        Bt[idx] = (_Float16)v;
    }
    if (idx < NCOLS) {
        float b;
        if      (idx < 128) b = bq[idx] * 0.125f;
        else if (idx < 256) b = bk[idx - 128];
        else if (idx < 384) b = bv[idx - 256];
        else                b = bs[idx - 384];
        bcat[idx] = b;
    }
}

// ---------------------------------------------------------------------------
// MFMA GEMM with LDS-staged B panel.
// 512 threads = 8 waves; chunk = 128 rows x 448 cols; wave = 16 rows.
// Bt[448][K] fp16 staged to LDS once per block with XOR swizzle
// (byte ^= (row&7)<<4) on BOTH write and read (bank-uniform for b128 reads).
// A-frag: one 16B global load/lane; B-frag: ds_read_b128 from swizzled LDS.
// C/D: row=(lane>>4)*4+reg, col=lane&15 (m89-verified).
// Split epilogue: q/skip -> qs fp32, k/v -> kvh fp16 chunk-interleaved.
// ---------------------------------------------------------------------------
template<int K>
__global__ __launch_bounds__(512) void gemm_mfma_kernel(
    const _Float16* __restrict__ Ah,   // [M][K]
    const _Float16* __restrict__ Bt,   // [448][K]
    const float* __restrict__ bias,    // [448]
    float* __restrict__ qs, __half* __restrict__ kvh, int M)
{
    __shared__ _Float16 Bs[NCOLS * K];   // 114.7KB (K=128) / 57.3KB (K=64)

    int tid  = threadIdx.x;
    int lane = tid & 63;
    int w    = tid >> 6;                 // 0..7
    int fr   = lane & 15;
    int g    = lane >> 4;

    // ---- stage B with swizzle: dest_byte = src_byte ^ ((row&7)<<4) ----
    constexpr int CH16 = NCOLS * K * 2 / 16;   // 16B chunks
    #pragma unroll
    for (int i = tid; i < CH16; i += 512) {
        int byte = i * 16;
        int row  = byte / (K * 2);
        int sw   = byte ^ ((row & 7) << 4);
        *(half8*)&Bs[sw >> 1] = *(const half8*)&Bt[byte >> 1];
    }
    __syncthreads();

    int nchunks = (M + 127) / 128;
    for (int ch = blockIdx.x; ch < nchunks; ch += gridDim.x) {
        int row0 = ch * 128 + w * 16;
        int arow = row0 + fr;
        if (arow > M - 1) arow = M - 1;    // clamp (stores guarded)

        f32x4 acc[28];
        #pragma unroll
        for (int c = 0; c < 28; ++c) acc[c] = (f32x4){0.f, 0.f, 0.f, 0.f};

        #pragma unroll
        for (int ks = 0; ks < K / 32; ++ks) {
            int k0 = ks * 32 + g * 8;
            half8 af = *(const half8*)&Ah[(size_t)arow * K + k0];
            #pragma unroll
            for (int c = 0; c < 28; ++c) {
                int row  = c * 16 + fr;
                int byte = (row * K + k0) * 2;
                int sw   = byte ^ ((row & 7) << 4);
                half8 bf = *(const half8*)&Bs[sw >> 1];
                acc[c] = __builtin_amdgcn_mfma_f32_16x16x32_f16(af, bf, acc[c], 0, 0, 0);
            }
        }

        #pragma unroll
        for (int c = 0; c < 28; ++c) {
            int col = c * 16 + fr;
            float bs = bias[col];
            #pragma unroll
            for (int j = 0; j < 4; ++j) {
                int row = row0 + g * 4 + j;
                if (row >= M) continue;
                float o = acc[c][j] + bs;
                if (col < 128) {
                    qs[(size_t)row * QS_COLS + col] = o;
                } else if (col >= 384) {
                    qs[(size_t)row * QS_COLS + 128 + (col - 384)] = o;
                } else {
                    int cc  = col - 128;
                    int mat = cc >> 7;          // 0=k, 1=v
                    int hh  = (cc >> 6) & 1;
                    int d   = cc & 63;
                    int pos = mat * 128 + (d >> 2) * 8 + hh * 4 + (d & 3);
                    kvh[(size_t)row * KV_COLS + pos] = __float2half_rn(o);
                }
            }
        }
    }
}

// ---------------------------------------------------------------------------
// CSR build: histogram -> 3-kernel parallel scan -> scatter
// ---------------------------------------------------------------------------
__global__ void hist_kernel(const int* __restrict__ dst, int* __restrict__ counts, int E)
{
    int i = blockIdx.x * 256 + threadIdx.x;
    if (i < E) atomicAdd(&counts[dst[i]], 1);
}

__global__ __launch_bounds__(256) void block_reduce_kernel(
    const int* __restrict__ counts, int* __restrict__ bsum, int N)
{
    __shared__ int s[256];
    int t = threadIdx.x;
    int i = blockIdx.x * 256 + t;
    s[t] = (i < N) ? counts[i] : 0;
    __syncthreads();
    #pragma unroll
    for (int o = 128; o; o >>= 1) {
        if (t < o) s[t] += s[t + o];
        __syncthreads();
    }
    if (t == 0) bsum[blockIdx.x] = s[0];
}

__global__ __launch_bounds__(256) void scan_partials_kernel(
    const int* __restrict__ bsum, int* __restrict__ boff, int nb, int* __restrict__ rowN)
{
    __shared__ int s[256];
    int t = threadIdx.x;
    int v = (t < nb) ? bsum[t] : 0;
    s[t] = v;
    __syncthreads();
    #pragma unroll
    for (int o = 1; o < 256; o <<= 1) {
        int x = (t >= o) ? s[t - o] : 0;
        __syncthreads();
        s[t] += x;
        __syncthreads();
    }
    if (t < nb) boff[t] = s[t] - v;     // exclusive
    if (t == nb - 1) rowN[0] = s[t];    // total = row_ptr[N]
}

__global__ __launch_bounds__(256) void block_scan_kernel(
    const int* __restrict__ counts, const int* __restrict__ boff,
    int* __restrict__ row_ptr, int* __restrict__ cursor, int N)
{
    __shared__ int s[256];
    int t = threadIdx.x;
    int i = blockIdx.x * 256 + t;
    int v = (i < N) ? counts[i] : 0;
    s[t] = v;
    __syncthreads();
    #pragma unroll
    for (int o = 1; o < 256; o <<= 1) {
        int x = (t >= o) ? s[t - o] : 0;
        __syncthreads();
        s[t] += x;
        __syncthreads();
    }
    if (i < N) {
        int excl = s[t] - v + boff[blockIdx.x];
        row_ptr[i] = excl;
        cursor[i]  = excl;
    }
}

__global__ void scatter_kernel(const int* __restrict__ ei, int* __restrict__ cursor,
                               int* __restrict__ src_sorted, int E)
{
    int i = blockIdx.x * 256 + threadIdx.x;
    if (i < E) {
        int d = ei[E + i];                    // dst
        int pos = atomicAdd(&cursor[d], 1);
        src_sorted[pos] = ei[i];              // src
    }
}

// ---------------------------------------------------------------------------
// DPP 16-lane sum (pure VALU)
// ---------------------------------------------------------------------------
__device__ __forceinline__ float dpp_sum16(float x)
{
    float t;
    t = __int_as_float(__builtin_amdgcn_mov_dpp(__float_as_int(x), 0xB1,  0xF, 0xF, true)); x += t; // xor 1
    t = __int_as_float(__builtin_amdgcn_mov_dpp(__float_as_int(x), 0x4E,  0xF, 0xF, true)); x += t; // xor 2
    t = __int_as_float(__builtin_amdgcn_mov_dpp(__float_as_int(x), 0x141, 0xF, 0xF, true)); x += t; // half-mirror
    t = __int_as_float(__builtin_amdgcn_mov_dpp(__float_as_int(x), 0x140, 0xF, 0xF, true)); x += t; // row-mirror
    return x;
}

// ---------------------------------------------------------------------------
// Fused edge kernel: one wave per dst node, 4 edge-groups x 16 lanes.
// Direct src_sorted[e] index loads (NO shfl preload — R4/R5 bug).
// fp16 K/V gathers: 2 x uint4 per lane per edge. Register double-buffer,
// DPP dot-reduce, flash merge, head-mean+skip+ReLU+LN.
// Writes h fp32 (pool) AND hh fp16 (next layer's GEMM A).
// ---------------------------------------------------------------------------
__global__ __launch_bounds__(256) void edge_conv_kernel(
    const float* __restrict__ qs, const __half* __restrict__ kvh,
    const int* __restrict__ row_ptr, const int* __restrict__ src_sorted,
    const float* __restrict__ gamma, const float* __restrict__ beta,
    float* __restrict__ hout, _Float16* __restrict__ hh, int N, int do_ln)
{
    int wave = threadIdx.x >> 6;
    int lane = threadIdx.x & 63;
    int g    = lane >> 4;        // edge-group 0..3
    int sub  = lane & 15;        // dim-chunk 0..15 (4 dims each)
    int node = blockIdx.x * 4 + wave;
    if (node >= N) return;

    const float* qb = qs + (size_t)node * QS_COLS;
    float4 q0 = *(const float4*)&qb[sub * 4];        // pre-scaled by 1/8
    float4 q1 = *(const float4*)&qb[64 + sub * 4];

    int e0 = row_ptr[node], e1 = row_ptr[node + 1];
    int deg = e1 - e0;

    float  m0 = -1e30f, m1 = -1e30f;
    float  s0 = 0.f, s1 = 0.f;
    float4 a0 = make_float4(0.f, 0.f, 0.f, 0.f);
    float4 a1 = make_float4(0.f, 0.f, 0.f, 0.f);

    int  e    = e0 + g;
    bool have = (e < e1);
    uint4 kraw, vraw;
    if (have) {
        int j = src_sorted[e];
        const __half* jb = kvh + (size_t)j * KV_COLS;
        kraw = *(const uint4*)&jb[sub * 8];
        vraw = *(const uint4*)&jb[128 + sub * 8];
    }

    while (have) {
        int  en    = e + 4;
        bool haven = (en < e1);
        uint4 krn, vrn;
        if (haven) {
            int jn = src_sorted[en];
            const __half* jbn = kvh + (size_t)jn * KV_COLS;
            krn = *(const uint4*)&jbn[sub * 8];
            vrn = *(const uint4*)&jbn[128 + sub * 8];
        }

        // unpack current K: 8 halves = k0(4 dims) | k1(4 dims)
        const __half2* kp = (const __half2*)&kraw;
        float2 ka = __half22float2(kp[0]), kb = __half22float2(kp[1]);
        float2 kc = __half22float2(kp[2]), kd = __half22float2(kp[3]);

        float p0 = fmaf(q0.w, kb.y, fmaf(q0.z, kb.x, fmaf(q0.y, ka.y, q0.x * ka.x)));
        float p1 = fmaf(q1.w, kd.y, fmaf(q1.z, kd.x, fmaf(q1.y, kc.y, q1.x * kc.x)));
        float sc0 = dpp_sum16(p0);
        float sc1 = dpp_sum16(p1);

        const __half2* vp = (const __half2*)&vraw;
        float2 va = __half22float2(vp[0]), vb = __half22float2(vp[1]);
        float2 vc = __half22float2(vp[2]), vd = __half22float2(vp[3]);

        float nm0 = fmaxf(m0, sc0);
        float f0  = __expf(m0 - nm0);
        float w0  = __expf(sc0 - nm0);
        s0 = fmaf(s0, f0, w0);
        a0.x = fmaf(a0.x, f0, w0 * va.x);
        a0.y = fmaf(a0.y, f0, w0 * va.y);
        a0.z = fmaf(a0.z, f0, w0 * vb.x);
        a0.w = fmaf(a0.w, f0, w0 * vb.y);
        m0 = nm0;

        float nm1 = fmaxf(m1, sc1);
        float f1  = __expf(m1 - nm1);
        float w1  = __expf(sc1 - nm1);
        s1 = fmaf(s1, f1, w1);
        a1.x = fmaf(a1.x, f1, w1 * vc.x);
        a1.y = fmaf(a1.y, f1, w1 * vc.y);
        a1.z = fmaf(a1.z, f1, w1 * vd.x);
        a1.w = fmaf(a1.w, f1, w1 * vd.y);
        m1 = nm1;

        kraw = krn; vraw = vrn; e = en; have = haven;
    }

    // merge flash states across the 4 groups (xor 16, then 32)
    #pragma unroll
    for (int offm = 16; offm <= 32; offm <<= 1) {
        float mo0 = __shfl_xor(m0, offm);
        float so0 = __shfl_xor(s0, offm);
        float4 ao0;
        ao0.x = __shfl_xor(a0.x, offm); ao0.y = __shfl_xor(a0.y, offm);
        ao0.z = __shfl_xor(a0.z, offm); ao0.w = __shfl_xor(a0.w, offm);
        float nm = fmaxf(m0, mo0);
        float fa = __expf(m0 - nm), fb = __expf(mo0 - nm);
        s0 = s0 * fa + so0 * fb;
        a0.x = a0.x * fa + ao0.x * fb; a0.y = a0.y * fa + ao0.y * fb;
        a0.z = a0.z * fa + ao0.z * fb; a0.w = a0.w * fa + ao0.w * fb;
        m0 = nm;

        float mo1 = __shfl_xor(m1, offm);
        float so1 = __shfl_xor(s1, offm);
        float4 ao1;
        ao1.x = __shfl_xor(a1.x, offm); ao1.y = __shfl_xor(a1.y, offm);
        ao1.z = __shfl_xor(a1.z, offm); ao1.w = __shfl_xor(a1.w, offm);
        nm = fmaxf(m1, mo1);
        fa = __expf(m1 - nm); fb = __expf(mo1 - nm);
        s1 = s1 * fa + so1 * fb;
        a1.x = a1.x * fa + ao1.x * fb; a1.y = a1.y * fa + ao1.y * fb;
        a1.z = a1.z * fa + ao1.z * fb; a1.w = a1.w * fa + ao1.w * fb;
        m1 = nm;
    }

    float4 skip = *(const float4*)&qb[128 + sub * 4];
    float4 o;
    if (deg > 0) {
        float r0 = 0.5f / s0, r1 = 0.5f / s1;
        o.x = a0.x * r0 + a1.x * r1 + skip.x;
        o.y = a0.y * r0 + a1.y * r1 + skip.y;
        o.z = a0.z * r0 + a1.z * r1 + skip.z;
        o.w = a0.w * r0 + a1.w * r1 + skip.w;
    } else {
        o = skip;
    }
    o.x = fmaxf(o.x, 0.f); o.y = fmaxf(o.y, 0.f);
    o.z = fmaxf(o.z, 0.f); o.w = fmaxf(o.w, 0.f);

    if (do_ln) {
        float mu = dpp_sum16(o.x + o.y + o.z + o.w) * (1.0f / 64.0f);
        float dx = o.x - mu, dy = o.y - mu, dz = o.z - mu, dw = o.w - mu;
        float var = dpp_sum16(dx * dx + dy * dy + dz * dz + dw * dw) * (1.0f / 64.0f);
        float rs = rsqrtf(var + LN_EPS);
        float4 gm = *(const float4*)&gamma[sub * 4];
        float4 bt = *(const float4*)&beta[sub * 4];
        o.x = dx * rs * gm.x + bt.x;
        o.y = dy * rs * gm.y + bt.y;
        o.z = dz * rs * gm.z + bt.z;
        o.w = dw * rs * gm.w + bt.w;
    }
    if (g == 0) {
        *(float4*)&hout[(size_t)node * HIDDEN + sub * 4] = o;
        __half2 h01 = __floats2half2_rn(o.x, o.y);
        __half2 h23 = __floats2half2_rn(o.z, o.w);
        uint2 pk;
        pk.x = *(unsigned int*)&h01;
        pk.y = *(unsigned int*)&h23;
        *(uint2*)&hh[(size_t)node * HIDDEN + sub * 4] = pk;
    }
}

// ---------------------------------------------------------------------------
// Pooling: batch is sorted; per-block register accumulation, rare atomic flush
// ---------------------------------------------------------------------------
#define POOL_NODES 256
__global__ __launch_bounds__(64) void pool_kernel(const float* __restrict__ h,
                                                  const int* __restrict__ batch,
                                                  float* __restrict__ pooled,
                                                  float* __restrict__ cnt, int N)
{
    int lane = threadIdx.x;
    int start = blockIdx.x * POOL_NODES;
    if (start >= N) return;
    int end = min(start + POOL_NODES, N);
    float acc = 0.f;
    int cur = batch[start];
    int c = 0;
    for (int i = start; i < end; ++i) {
        int b = batch[i];
        if (b != cur) {
            atomicAdd(&pooled[cur * HIDDEN + lane], acc);
            if (lane == 0) atomicAdd(&cnt[cur], (float)c);
            acc = 0.f; c = 0; cur = b;
        }
        acc += h[(size_t)i * HIDDEN + lane];
        ++c;
    }
    atomicAdd(&pooled[cur * HIDDEN + lane], acc);
    if (lane == 0) atomicAdd(&cnt[cur], (float)c);
}

__global__ void final_kernel(const float* __restrict__ pooled, const float* __restrict__ cnt,
                             const float* __restrict__ Wp, const float* __restrict__ bp,
                             float* __restrict__ out)
{
    int g = threadIdx.x;   // 64 graphs
    float c = fmaxf(cnt[g], 1.0f);
    float s = 0.f;
    for (int d = 0; d < HIDDEN; ++d) s += pooled[g * HIDDEN + d] * Wp[d];
    out[g] = s / c + bp[0];
}

// ---------------------------------------------------------------------------
// Host launcher
// ---------------------------------------------------------------------------
extern "C" void kernel_launch(void* const* d_in, const int* in_sizes, int n_in,
                              void* d_out, int out_size, void* d_ws, size_t ws_size,
                              hipStream_t stream)
{
    const float* x    = (const float*)d_in[0];
    const int*   ei   = (const int*)d_in[1];
    const int*   batch= (const int*)d_in[2];

    const float* Wl[3][4];  // Wq, Wk, Wv, Ws
    const float* bl[3][4];  // bq, bk, bv, bs
    for (int l = 0; l < 3; ++l) {
        int b = 3 + l * 8;
        Wl[l][0] = (const float*)d_in[b + 0]; bl[l][0] = (const float*)d_in[b + 1];
        Wl[l][1] = (const float*)d_in[b + 2]; bl[l][1] = (const float*)d_in[b + 3];
        Wl[l][2] = (const float*)d_in[b + 4]; bl[l][2] = (const float*)d_in[b + 5];
        Wl[l][3] = (const float*)d_in[b + 6]; bl[l][3] = (const float*)d_in[b + 7];
    }
    const float* g0    = (const float*)d_in[27];
    const float* beta0 = (const float*)d_in[28];
    const float* g1    = (const float*)d_in[29];
    const float* beta1 = (const float*)d_in[30];
    const float* Wp    = (const float*)d_in[31];
    const float* bp    = (const float*)d_in[32];

    const int N = in_sizes[0] / 128;   // 50000
    const int E = in_sizes[1] / 2;     // 800000

    // workspace carve (256B aligned)
    size_t off = 0;
    auto carve = [&](size_t bytes) -> char* {
        char* p = (char*)d_ws + off;
        off = (off + bytes + 255) & ~(size_t)255;
        return p;
    };
    float*     qs     = (float*)carve((size_t)N * QS_COLS * 4);
    __half*    kvh    = (__half*)carve((size_t)N * KV_COLS * 2);
    float*     h      = (float*)carve((size_t)N * HIDDEN * 4);
    _Float16*  hh     = (_Float16*)carve((size_t)N * HIDDEN * 2);
    _Float16*  xh     = (_Float16*)carve((size_t)N * 128 * 2);
    _Float16*  Bt     = (_Float16*)carve((size_t)NCOLS * 128 * 2);
    float*     bcat   = (float*)carve(NCOLS * 4);
    int*       counts = (int*)carve((size_t)N * 4);
    int*       row_ptr= (int*)carve((size_t)(N + 1) * 4);
    int*       cursor = (int*)carve((size_t)N * 4);
    int*       src_sorted = (int*)carve((size_t)E * 4);
    int*       bsum   = (int*)carve(1024 * 4);
    int*       boff   = (int*)carve(1024 * 4);
    float*     pooled = (float*)carve((size_t)(N_GRAPHS * HIDDEN + N_GRAPHS) * 4);
    float*     cntf   = pooled + N_GRAPHS * HIDDEN;

    const int nb = (N + 255) / 256;    // 196 scan blocks

    // ---- CSR build (dst is layer-invariant) ----
    hipMemsetAsync(counts, 0, (size_t)N * 4, stream);
    hist_kernel<<<(E + 255) / 256, 256, 0, stream>>>(ei + E, counts, E);
    block_reduce_kernel<<<nb, 256, 0, stream>>>(counts, bsum, N);
    scan_partials_kernel<<<1, 256, 0, stream>>>(bsum, boff, nb, &row_ptr[N]);
    block_scan_kernel<<<nb, 256, 0, stream>>>(counts, boff, row_ptr, cursor, N);
    scatter_kernel<<<(E + 255) / 256, 256, 0, stream>>>(ei, cursor, src_sorted, E);

    // ---- cast x to fp16 once ----
    {
        int n4 = (N * 128) / 4;
        cast_f2h_kernel<<<(n4 + 255) / 256, 256, 0, stream>>>(x, xh, n4);
    }

    const int nchunks = (N + 127) / 128;   // 391

    // ---- 3 TransformerConv layers ----
    for (int l = 0; l < 3; ++l) {
        int K = (l == 0) ? 128 : 64;
        int packTot = NCOLS * K;
        pack_kernel<<<(packTot + 255) / 256, 256, 0, stream>>>(
            Wl[l][0], Wl[l][1], Wl[l][2], Wl[l][3],
            bl[l][0], bl[l][1], bl[l][2], bl[l][3], Bt, bcat, K);
        if (l == 0)
            gemm_mfma_kernel<128><<<nchunks, 512, 0, stream>>>(xh, Bt, bcat, qs, kvh, N);
        else
            gemm_mfma_kernel<64><<<nchunks, 512, 0, stream>>>(hh, Bt, bcat, qs, kvh, N);
        int do_ln = (l < 2) ? 1 : 0;
        const float* gg = (l == 0) ? g0 : g1;
        const float* bb = (l == 0) ? beta0 : beta1;
        edge_conv_kernel<<<(N + 3) / 4, 256, 0, stream>>>(
            qs, kvh, row_ptr, src_sorted, gg, bb, h, hh, N, do_ln);
    }

    // ---- global mean pool + head ----
    hipMemsetAsync(pooled, 0, (size_t)(N_GRAPHS * HIDDEN + N_GRAPHS) * 4, stream);
    pool_kernel<<<(N + POOL_NODES - 1) / POOL_NODES, 64, 0, stream>>>(h, batch, pooled, cntf, N);
    final_kernel<<<1, 64, 0, stream>>>(pooled, cntf, Wp, bp, (float*)d_out);
}

// Round 10
// 464.790 us; speedup vs baseline: 1.7792x; 1.0463x over previous
//
#include <hip/hip_runtime.h>
#include <hip/hip_fp16.h>
#include <math.h>

// ---------------------------------------------------------------------------
// Problem constants (from reference)
// ---------------------------------------------------------------------------
#define HIDDEN 64
#define HEADS 2
#define NCOLS 448          // GEMM logical cols: q(128) k(128) v(128) s(64)
#define QS_COLS 192        // fp32: q0 q1 (128) + skip (64)
#define KV_COLS 256        // fp16 halves: chunk-interleaved k/v
#define N_GRAPHS 64
#define LN_EPS 1e-5f

typedef _Float16 half8 __attribute__((ext_vector_type(8)));
typedef float    f32x4 __attribute__((ext_vector_type(4)));

// kvh element index for head h, dim d, mat(0=k,1=v): mat*128 + (d>>2)*8 + h*4 + (d&3)

// ---------------------------------------------------------------------------
// Cast fp32 -> fp16, vectorized (n multiple of 4)
// ---------------------------------------------------------------------------
__global__ void cast_f2h_kernel(const float* __restrict__ in, _Float16* __restrict__ out, int n4)
{
    int i = blockIdx.x * 256 + threadIdx.x;
    if (i < n4) {
        float4 v = *(const float4*)&in[i * 4];
        __half2 a = __floats2half2_rn(v.x, v.y);
        __half2 b = __floats2half2_rn(v.z, v.w);
        uint2 pk;
        pk.x = *(unsigned int*)&a;
        pk.y = *(unsigned int*)&b;
        *(uint2*)&out[i * 4] = pk;
    }
}

// ---------------------------------------------------------------------------
// Weight pack (transposed, fp16): Bt[448][K], Bt[c][k] = W[k][c] (q scaled
// by 0.125 — exact pow2). bcat[448] fp32.
// ---------------------------------------------------------------------------
__global__ void pack_kernel(const float* __restrict__ Wq, const float* __restrict__ Wk,
                            const float* __restrict__ Wv, const float* __restrict__ Ws,
                            const float* __restrict__ bq, const float* __restrict__ bk,
                            const float* __restrict__ bv, const float* __restrict__ bs,
                            _Float16* __restrict__ Bt, float* __restrict__ bcat, int K)
{
    int idx = blockIdx.x * 256 + threadIdx.x;
    int total = NCOLS * K;
    if (idx < total) {
        int c = idx / K, k = idx - c * K;
        float v;
        if      (c < 128) v = Wq[k * 128 + c] * 0.125f;
        else if (c < 256) v = Wk[k * 128 + (c - 128)];
        else if (c < 384) v = Wv[k * 128 + (c - 256)];
        else              v = Ws[k * 64  + (c - 384)];
        Bt[idx] = (_Float16)v;
    }
    if (idx < NCOLS) {
        float b;
        if      (idx < 128) b = bq[idx] * 0.125f;
        else if (idx < 256) b = bk[idx - 128];
        else if (idx < 384) b = bv[idx - 256];
        else                b = bs[idx - 384];
        bcat[idx] = b;
    }
}

// ---------------------------------------------------------------------------
// MFMA GEMM body: one wave = 16 rows x NT*16 cols, fp32 accum.
// B-frags from XOR-swizzled LDS (byte ^ (row&7)<<4, same involution as the
// staging writes). A-frag: one 16B global load per lane per k-step.
// C/D mapping: row=(lane>>4)*4+reg, col=lane&15 (m89-verified).
// ---------------------------------------------------------------------------
template<int K, int NT>
__device__ __forceinline__ void gemm_body(
    const _Float16* __restrict__ Ah, const float* __restrict__ bias,
    float* __restrict__ qs, __half* __restrict__ kvh,
    const _Float16* Bs, int M, int colBase, int chunkRow0, int tid)
{
    int lane = tid & 63;
    int w    = tid >> 6;              // 0..7
    int fr   = lane & 15;
    int g    = lane >> 4;
    int row0 = chunkRow0 + w * 16;
    int arow = row0 + fr;
    if (arow > M - 1) arow = M - 1;   // clamp (stores guarded)

    f32x4 acc[NT];
    #pragma unroll
    for (int c = 0; c < NT; ++c) acc[c] = (f32x4){0.f, 0.f, 0.f, 0.f};

    #pragma unroll
    for (int ks = 0; ks < K / 32; ++ks) {
        int k0 = ks * 32 + g * 8;
        half8 af = *(const half8*)&Ah[(size_t)arow * K + k0];
        #pragma unroll
        for (int c = 0; c < NT; ++c) {
            int rl   = c * 16 + fr;
            int byte = rl * (K * 2) + k0 * 2;
            int sw   = byte ^ ((rl & 7) << 4);
            half8 bf = *(const half8*)((const char*)Bs + sw);
            acc[c] = __builtin_amdgcn_mfma_f32_16x16x32_f16(af, bf, acc[c], 0, 0, 0);
        }
    }

    #pragma unroll
    for (int c = 0; c < NT; ++c) {
        int col = colBase + c * 16 + fr;
        float bs = bias[col];
        #pragma unroll
        for (int j = 0; j < 4; ++j) {
            int row = row0 + g * 4 + j;
            if (row >= M) continue;
            float o = acc[c][j] + bs;
            if (col < 128) {
                qs[(size_t)row * QS_COLS + col] = o;
            } else if (col >= 384) {
                qs[(size_t)row * QS_COLS + 128 + (col - 384)] = o;
            } else {
                int cc  = col - 128;
                int mat = cc >> 7;          // 0=k, 1=v
                int hh  = (cc >> 6) & 1;
                int d   = cc & 63;
                int pos = mat * 128 + (d >> 2) * 8 + hh * 4 + (d & 3);
                kvh[(size_t)row * KV_COLS + pos] = __float2half_rn(o);
            }
        }
    }
}

// ---------------------------------------------------------------------------
// MFMA GEMM kernel: 512 threads = 8 waves, chunk = 128 rows.
// Column-split: blockIdx.x&1==0 -> q+k (cols 0..255, Bs 64KB @K=128);
//               ==1 -> v+skip (cols 256..447, 48KB). 2 blocks/CU co-resident
// (launch_bounds(512,4) caps VGPR<=128) -> 16 waves/CU vs R9's 8.
// Split keeps k0/k1 (and v0/v1) in one block: no cross-block kvh-chunk or
// L2-line co-writes.
// ---------------------------------------------------------------------------
template<int K>
__global__ __launch_bounds__(512, 4) void gemm_mfma_kernel(
    const _Float16* __restrict__ Ah,   // [M][K]
    const _Float16* __restrict__ Bt,   // [448][K]
    const float* __restrict__ bias,    // [448]
    float* __restrict__ qs, __half* __restrict__ kvh, int M)
{
    __shared__ _Float16 Bs[256 * K];   // 64KB (K=128) / 32KB (K=64)

    int tid    = threadIdx.x;
    int colblk = blockIdx.x & 1;
    int chunk  = blockIdx.x >> 1;
    int colBase = colblk ? 256 : 0;
    int cols    = colblk ? 192 : 256;

    // stage B panel with swizzle: dest_byte = src_byte ^ ((row&7)<<4)
    int bytes = cols * K * 2;
    const char* src = (const char*)Bt + (size_t)colBase * K * 2;
    for (int i = tid * 16; i < bytes; i += 512 * 16) {
        int rl = i / (K * 2);
        int sw = i ^ ((rl & 7) << 4);
        *(half8*)((char*)Bs + sw) = *(const half8*)(src + i);
    }
    __syncthreads();

    if (colblk == 0)
        gemm_body<K, 16>(Ah, bias, qs, kvh, Bs, M, 0,   chunk * 128, tid);
    else
        gemm_body<K, 12>(Ah, bias, qs, kvh, Bs, M, 256, chunk * 128, tid);
}

// ---------------------------------------------------------------------------
// CSR build: histogram -> 3-kernel parallel scan -> scatter
// ---------------------------------------------------------------------------
__global__ void hist_kernel(const int* __restrict__ dst, int* __restrict__ counts, int E)
{
    int i = blockIdx.x * 256 + threadIdx.x;
    if (i < E) atomicAdd(&counts[dst[i]], 1);
}

__global__ __launch_bounds__(256) void block_reduce_kernel(
    const int* __restrict__ counts, int* __restrict__ bsum, int N)
{
    __shared__ int s[256];
    int t = threadIdx.x;
    int i = blockIdx.x * 256 + t;
    s[t] = (i < N) ? counts[i] : 0;
    __syncthreads();
    #pragma unroll
    for (int o = 128; o; o >>= 1) {
        if (t < o) s[t] += s[t + o];
        __syncthreads();
    }
    if (t == 0) bsum[blockIdx.x] = s[0];
}

__global__ __launch_bounds__(256) void scan_partials_kernel(
    const int* __restrict__ bsum, int* __restrict__ boff, int nb, int* __restrict__ rowN)
{
    __shared__ int s[256];
    int t = threadIdx.x;
    int v = (t < nb) ? bsum[t] : 0;
    s[t] = v;
    __syncthreads();
    #pragma unroll
    for (int o = 1; o < 256; o <<= 1) {
        int x = (t >= o) ? s[t - o] : 0;
        __syncthreads();
        s[t] += x;
        __syncthreads();
    }
    if (t < nb) boff[t] = s[t] - v;     // exclusive
    if (t == nb - 1) rowN[0] = s[t];    // total = row_ptr[N]
}

__global__ __launch_bounds__(256) void block_scan_kernel(
    const int* __restrict__ counts, const int* __restrict__ boff,
    int* __restrict__ row_ptr, int* __restrict__ cursor, int N)
{
    __shared__ int s[256];
    int t = threadIdx.x;
    int i = blockIdx.x * 256 + t;
    int v = (i < N) ? counts[i] : 0;
    s[t] = v;
    __syncthreads();
    #pragma unroll
    for (int o = 1; o < 256; o <<= 1) {
        int x = (t >= o) ? s[t - o] : 0;
        __syncthreads();
        s[t] += x;
        __syncthreads();
    }
    if (i < N) {
        int excl = s[t] - v + boff[blockIdx.x];
        row_ptr[i] = excl;
        cursor[i]  = excl;
    }
}

__global__ void scatter_kernel(const int* __restrict__ ei, int* __restrict__ cursor,
                               int* __restrict__ src_sorted, int E)
{
    int i = blockIdx.x * 256 + threadIdx.x;
    if (i < E) {
        int d = ei[E + i];                    // dst
        int pos = atomicAdd(&cursor[d], 1);
        src_sorted[pos] = ei[i];              // src
    }
}

// ---------------------------------------------------------------------------
// DPP 16-lane sum (pure VALU)
// ---------------------------------------------------------------------------
__device__ __forceinline__ float dpp_sum16(float x)
{
    float t;
    t = __int_as_float(__builtin_amdgcn_mov_dpp(__float_as_int(x), 0xB1,  0xF, 0xF, true)); x += t; // xor 1
    t = __int_as_float(__builtin_amdgcn_mov_dpp(__float_as_int(x), 0x4E,  0xF, 0xF, true)); x += t; // xor 2
    t = __int_as_float(__builtin_amdgcn_mov_dpp(__float_as_int(x), 0x141, 0xF, 0xF, true)); x += t; // half-mirror
    t = __int_as_float(__builtin_amdgcn_mov_dpp(__float_as_int(x), 0x140, 0xF, 0xF, true)); x += t; // row-mirror
    return x;
}

// ---------------------------------------------------------------------------
// Fused edge kernel: one wave per dst node, 4 edge-groups x 16 lanes.
// Direct src_sorted[e] index loads (NO shfl preload — R4/R5 bug).
// fp16 K/V gathers: 2 x uint4 per lane per edge. Register double-buffer,
// DPP dot-reduce, flash merge, head-mean+skip+ReLU+LN.
// Writes h fp32 (pool) AND hh fp16 (next layer's GEMM A).
// ---------------------------------------------------------------------------
__global__ __launch_bounds__(256) void edge_conv_kernel(
    const float* __restrict__ qs, const __half* __restrict__ kvh,
    const int* __restrict__ row_ptr, const int* __restrict__ src_sorted,
    const float* __restrict__ gamma, const float* __restrict__ beta,
    float* __restrict__ hout, _Float16* __restrict__ hh, int N, int do_ln)
{
    int wave = threadIdx.x >> 6;
    int lane = threadIdx.x & 63;
    int g    = lane >> 4;        // edge-group 0..3
    int sub  = lane & 15;        // dim-chunk 0..15 (4 dims each)
    int node = blockIdx.x * 4 + wave;
    if (node >= N) return;

    const float* qb = qs + (size_t)node * QS_COLS;
    float4 q0 = *(const float4*)&qb[sub * 4];        // pre-scaled by 1/8
    float4 q1 = *(const float4*)&qb[64 + sub * 4];

    int e0 = row_ptr[node], e1 = row_ptr[node + 1];
    int deg = e1 - e0;

    float  m0 = -1e30f, m1 = -1e30f;
    float  s0 = 0.f, s1 = 0.f;
    float4 a0 = make_float4(0.f, 0.f, 0.f, 0.f);
    float4 a1 = make_float4(0.f, 0.f, 0.f, 0.f);

    int  e    = e0 + g;
    bool have = (e < e1);
    uint4 kraw, vraw;
    if (have) {
        int j = src_sorted[e];
        const __half* jb = kvh + (size_t)j * KV_COLS;
        kraw = *(const uint4*)&jb[sub * 8];
        vraw = *(const uint4*)&jb[128 + sub * 8];
    }

    while (have) {
        int  en    = e + 4;
        bool haven = (en < e1);
        uint4 krn, vrn;
        if (haven) {
            int jn = src_sorted[en];
            const __half* jbn = kvh + (size_t)jn * KV_COLS;
            krn = *(const uint4*)&jbn[sub * 8];
            vrn = *(const uint4*)&jbn[128 + sub * 8];
        }

        // unpack current K: 8 halves = k0(4 dims) | k1(4 dims)
        const __half2* kp = (const __half2*)&kraw;
        float2 ka = __half22float2(kp[0]), kb = __half22float2(kp[1]);
        float2 kc = __half22float2(kp[2]), kd = __half22float2(kp[3]);

        float p0 = fmaf(q0.w, kb.y, fmaf(q0.z, kb.x, fmaf(q0.y, ka.y, q0.x * ka.x)));
        float p1 = fmaf(q1.w, kd.y, fmaf(q1.z, kd.x, fmaf(q1.y, kc.y, q1.x * kc.x)));
        float sc0 = dpp_sum16(p0);
        float sc1 = dpp_sum16(p1);

        const __half2* vp = (const __half2*)&vraw;
        float2 va = __half22float2(vp[0]), vb = __half22float2(vp[1]);
        float2 vc = __half22float2(vp[2]), vd = __half22float2(vp[3]);

        float nm0 = fmaxf(m0, sc0);
        float f0  = __expf(m0 - nm0);
        float w0  = __expf(sc0 - nm0);
        s0 = fmaf(s0, f0, w0);
        a0.x = fmaf(a0.x, f0, w0 * va.x);
        a0.y = fmaf(a0.y, f0, w0 * va.y);
        a0.z = fmaf(a0.z, f0, w0 * vb.x);
        a0.w = fmaf(a0.w, f0, w0 * vb.y);
        m0 = nm0;

        float nm1 = fmaxf(m1, sc1);
        float f1  = __expf(m1 - nm1);
        float w1  = __expf(sc1 - nm1);
        s1 = fmaf(s1, f1, w1);
        a1.x = fmaf(a1.x, f1, w1 * vc.x);
        a1.y = fmaf(a1.y, f1, w1 * vc.y);
        a1.z = fmaf(a1.z, f1, w1 * vd.x);
        a1.w = fmaf(a1.w, f1, w1 * vd.y);
        m1 = nm1;

        kraw = krn; vraw = vrn; e = en; have = haven;
    }

    // merge flash states across the 4 groups (xor 16, then 32)
    #pragma unroll
    for (int offm = 16; offm <= 32; offm <<= 1) {
        float mo0 = __shfl_xor(m0, offm);
        float so0 = __shfl_xor(s0, offm);
        float4 ao0;
        ao0.x = __shfl_xor(a0.x, offm); ao0.y = __shfl_xor(a0.y, offm);
        ao0.z = __shfl_xor(a0.z, offm); ao0.w = __shfl_xor(a0.w, offm);
        float nm = fmaxf(m0, mo0);
        float fa = __expf(m0 - nm), fb = __expf(mo0 - nm);
        s0 = s0 * fa + so0 * fb;
        a0.x = a0.x * fa + ao0.x * fb; a0.y = a0.y * fa + ao0.y * fb;
        a0.z = a0.z * fa + ao0.z * fb; a0.w = a0.w * fa + ao0.w * fb;
        m0 = nm;

        float mo1 = __shfl_xor(m1, offm);
        float so1 = __shfl_xor(s1, offm);
        float4 ao1;
        ao1.x = __shfl_xor(a1.x, offm); ao1.y = __shfl_xor(a1.y, offm);
        ao1.z = __shfl_xor(a1.z, offm); ao1.w = __shfl_xor(a1.w, offm);
        nm = fmaxf(m1, mo1);
        fa = __expf(m1 - nm); fb = __expf(mo1 - nm);
        s1 = s1 * fa + so1 * fb;
        a1.x = a1.x * fa + ao1.x * fb; a1.y = a1.y * fa + ao1.y * fb;
        a1.z = a1.z * fa + ao1.z * fb; a1.w = a1.w * fa + ao1.w * fb;
        m1 = nm;
    }

    float4 skip = *(const float4*)&qb[128 + sub * 4];
    float4 o;
    if (deg > 0) {
        float r0 = 0.5f / s0, r1 = 0.5f / s1;
        o.x = a0.x * r0 + a1.x * r1 + skip.x;
        o.y = a0.y * r0 + a1.y * r1 + skip.y;
        o.z = a0.z * r0 + a1.z * r1 + skip.z;
        o.w = a0.w * r0 + a1.w * r1 + skip.w;
    } else {
        o = skip;
    }
    o.x = fmaxf(o.x, 0.f); o.y = fmaxf(o.y, 0.f);
    o.z = fmaxf(o.z, 0.f); o.w = fmaxf(o.w, 0.f);

    if (do_ln) {
        float mu = dpp_sum16(o.x + o.y + o.z + o.w) * (1.0f / 64.0f);
        float dx = o.x - mu, dy = o.y - mu, dz = o.z - mu, dw = o.w - mu;
        float var = dpp_sum16(dx * dx + dy * dy + dz * dz + dw * dw) * (1.0f / 64.0f);
        float rs = rsqrtf(var + LN_EPS);
        float4 gm = *(const float4*)&gamma[sub * 4];
        float4 bt = *(const float4*)&beta[sub * 4];
        o.x = dx * rs * gm.x + bt.x;
        o.y = dy * rs * gm.y + bt.y;
        o.z = dz * rs * gm.z + bt.z;
        o.w = dw * rs * gm.w + bt.w;
    }
    if (g == 0) {
        *(float4*)&hout[(size_t)node * HIDDEN + sub * 4] = o;
        __half2 h01 = __floats2half2_rn(o.x, o.y);
        __half2 h23 = __floats2half2_rn(o.z, o.w);
        uint2 pk;
        pk.x = *(unsigned int*)&h01;
        pk.y = *(unsigned int*)&h23;
        *(uint2*)&hh[(size_t)node * HIDDEN + sub * 4] = pk;
    }
}

// ---------------------------------------------------------------------------
// Pooling: batch is sorted; per-block register accumulation, rare atomic flush
// ---------------------------------------------------------------------------
#define POOL_NODES 256
__global__ __launch_bounds__(64) void pool_kernel(const float* __restrict__ h,
                                                  const int* __restrict__ batch,
                                                  float* __restrict__ pooled,
                                                  float* __restrict__ cnt, int N)
{
    int lane = threadIdx.x;
    int start = blockIdx.x * POOL_NODES;
    if (start >= N) return;
    int end = min(start + POOL_NODES, N);
    float acc = 0.f;
    int cur = batch[start];
    int c = 0;
    for (int i = start; i < end; ++i) {
        int b = batch[i];
        if (b != cur) {
            atomicAdd(&pooled[cur * HIDDEN + lane], acc);
            if (lane == 0) atomicAdd(&cnt[cur], (float)c);
            acc = 0.f; c = 0; cur = b;
        }
        acc += h[(size_t)i * HIDDEN + lane];
        ++c;
    }
    atomicAdd(&pooled[cur * HIDDEN + lane], acc);
    if (lane == 0) atomicAdd(&cnt[cur], (float)c);
}

__global__ void final_kernel(const float* __restrict__ pooled, const float* __restrict__ cnt,
                             const float* __restrict__ Wp, const float* __restrict__ bp,
                             float* __restrict__ out)
{
    int g = threadIdx.x;   // 64 graphs
    float c = fmaxf(cnt[g], 1.0f);
    float s = 0.f;
    for (int d = 0; d < HIDDEN; ++d) s += pooled[g * HIDDEN + d] * Wp[d];
    out[g] = s / c + bp[0];
}

// ---------------------------------------------------------------------------
// Host launcher
// ---------------------------------------------------------------------------
extern "C" void kernel_launch(void* const* d_in, const int* in_sizes, int n_in,
                              void* d_out, int out_size, void* d_ws, size_t ws_size,
                              hipStream_t stream)
{
    const float* x    = (const float*)d_in[0];
    const int*   ei   = (const int*)d_in[1];
    const int*   batch= (const int*)d_in[2];

    const float* Wl[3][4];  // Wq, Wk, Wv, Ws
    const float* bl[3][4];  // bq, bk, bv, bs
    for (int l = 0; l < 3; ++l) {
        int b = 3 + l * 8;
        Wl[l][0] = (const float*)d_in[b + 0]; bl[l][0] = (const float*)d_in[b + 1];
        Wl[l][1] = (const float*)d_in[b + 2]; bl[l][1] = (const float*)d_in[b + 3];
        Wl[l][2] = (const float*)d_in[b + 4]; bl[l][2] = (const float*)d_in[b + 5];
        Wl[l][3] = (const float*)d_in[b + 6]; bl[l][3] = (const float*)d_in[b + 7];
    }
    const float* g0    = (const float*)d_in[27];
    const float* beta0 = (const float*)d_in[28];
    const float* g1    = (const float*)d_in[29];
    const float* beta1 = (const float*)d_in[30];
    const float* Wp    = (const float*)d_in[31];
    const float* bp    = (const float*)d_in[32];

    const int N = in_sizes[0] / 128;   // 50000
    const int E = in_sizes[1] / 2;     // 800000

    // workspace carve (256B aligned)
    size_t off = 0;
    auto carve = [&](size_t bytes) -> char* {
        char* p = (char*)d_ws + off;
        off = (off + bytes + 255) & ~(size_t)255;
        return p;
    };
    float*     qs     = (float*)carve((size_t)N * QS_COLS * 4);
    __half*    kvh    = (__half*)carve((size_t)N * KV_COLS * 2);
    float*     h      = (float*)carve((size_t)N * HIDDEN * 4);
    _Float16*  hh     = (_Float16*)carve((size_t)N * HIDDEN * 2);
    _Float16*  xh     = (_Float16*)carve((size_t)N * 128 * 2);
    _Float16*  Bt     = (_Float16*)carve((size_t)NCOLS * 128 * 2);
    float*     bcat   = (float*)carve(NCOLS * 4);
    int*       counts = (int*)carve((size_t)N * 4);
    int*       row_ptr= (int*)carve((size_t)(N + 1) * 4);
    int*       cursor = (int*)carve((size_t)N * 4);
    int*       src_sorted = (int*)carve((size_t)E * 4);
    int*       bsum   = (int*)carve(1024 * 4);
    int*       boff   = (int*)carve(1024 * 4);
    float*     pooled = (float*)carve((size_t)(N_GRAPHS * HIDDEN + N_GRAPHS) * 4);
    float*     cntf   = pooled + N_GRAPHS * HIDDEN;

    const int nb = (N + 255) / 256;    // 196 scan blocks

    // ---- CSR build (dst is layer-invariant) ----
    hipMemsetAsync(counts, 0, (size_t)N * 4, stream);
    hist_kernel<<<(E + 255) / 256, 256, 0, stream>>>(ei + E, counts, E);
    block_reduce_kernel<<<nb, 256, 0, stream>>>(counts, bsum, N);
    scan_partials_kernel<<<1, 256, 0, stream>>>(bsum, boff, nb, &row_ptr[N]);
    block_scan_kernel<<<nb, 256, 0, stream>>>(counts, boff, row_ptr, cursor, N);
    scatter_kernel<<<(E + 255) / 256, 256, 0, stream>>>(ei, cursor, src_sorted, E);

    // ---- cast x to fp16 once ----
    {
        int n4 = (N * 128) / 4;
        cast_f2h_kernel<<<(n4 + 255) / 256, 256, 0, stream>>>(x, xh, n4);
    }

    const int gemm_grid = 2 * ((N + 127) / 128);   // 2 col-blocks x 391 row-chunks

    // ---- 3 TransformerConv layers ----
    for (int l = 0; l < 3; ++l) {
        int K = (l == 0) ? 128 : 64;
        int packTot = NCOLS * K;
        pack_kernel<<<(packTot + 255) / 256, 256, 0, stream>>>(
            Wl[l][0], Wl[l][1], Wl[l][2], Wl[l][3],
            bl[l][0], bl[l][1], bl[l][2], bl[l][3], Bt, bcat, K);
        if (l == 0)
            gemm_mfma_kernel<128><<<gemm_grid, 512, 0, stream>>>(xh, Bt, bcat, qs, kvh, N);
        else
            gemm_mfma_kernel<64><<<gemm_grid, 512, 0, stream>>>(hh, Bt, bcat, qs, kvh, N);
        int do_ln = (l < 2) ? 1 : 0;
        const float* gg = (l == 0) ? g0 : g1;
        const float* bb = (l == 0) ? beta0 : beta1;
        edge_conv_kernel<<<(N + 3) / 4, 256, 0, stream>>>(
            qs, kvh, row_ptr, src_sorted, gg, bb, h, hh, N, do_ln);
    }

    // ---- global mean pool + head ----
    hipMemsetAsync(pooled, 0, (size_t)(N_GRAPHS * HIDDEN + N_GRAPHS) * 4, stream);
    pool_kernel<<<(N + POOL_NODES - 1) / POOL_NODES, 64, 0, stream>>>(h, batch, pooled, cntf, N);
    final_kernel<<<1, 64, 0, stream>>>(pooled, cntf, Wp, bp, (float*)d_out);
}

// Round 11
// 415.258 us; speedup vs baseline: 1.9914x; 1.1193x over previous
//
#include <hip/hip_runtime.h>
#include <hip/hip_fp16.h>
#include <math.h>

// ---------------------------------------------------------------------------
// Problem constants (from reference)
// ---------------------------------------------------------------------------
#define HIDDEN 64
#define HEADS 2
#define NCOLS 448          // GEMM logical cols: q(128) k(128) v(128) s(64)
#define QS_COLS 192        // fp32: q0 q1 (128) + skip (64)
#define KV_COLS 256        // fp16 halves: chunk-interleaved k/v
#define N_GRAPHS 64
#define LN_EPS 1e-5f

typedef _Float16 half8 __attribute__((ext_vector_type(8)));
typedef float    f32x4 __attribute__((ext_vector_type(4)));

// kvh element index for head h, dim d, mat(0=k,1=v): mat*128 + (d>>2)*8 + h*4 + (d&3)

// ---------------------------------------------------------------------------
// Cast fp32 -> fp16, vectorized (n multiple of 4)
// ---------------------------------------------------------------------------
__global__ void cast_f2h_kernel(const float* __restrict__ in, _Float16* __restrict__ out, int n4)
{
    int i = blockIdx.x * 256 + threadIdx.x;
    if (i < n4) {
        float4 v = *(const float4*)&in[i * 4];
        __half2 a = __floats2half2_rn(v.x, v.y);
        __half2 b = __floats2half2_rn(v.z, v.w);
        uint2 pk;
        pk.x = *(unsigned int*)&a;
        pk.y = *(unsigned int*)&b;
        *(uint2*)&out[i * 4] = pk;
    }
}

// ---------------------------------------------------------------------------
// Weight pack (transposed, fp16): Bt[448][K], Bt[c][k] = W[k][c] (q scaled
// by 0.125 — exact pow2). bcat[448] fp32.
// ---------------------------------------------------------------------------
__global__ void pack_kernel(const float* __restrict__ Wq, const float* __restrict__ Wk,
                            const float* __restrict__ Wv, const float* __restrict__ Ws,
                            const float* __restrict__ bq, const float* __restrict__ bk,
                            const float* __restrict__ bv, const float* __restrict__ bs,
                            _Float16* __restrict__ Bt, float* __restrict__ bcat, int K)
{
    int idx = blockIdx.x * 256 + threadIdx.x;
    int total = NCOLS * K;
    if (idx < total) {
        int c = idx / K, k = idx - c * K;
        float v;
        if      (c < 128) v = Wq[k * 128 + c] * 0.125f;
        else if (c < 256) v = Wk[k * 128 + (c - 128)];
        else if (c < 384) v = Wv[k * 128 + (c - 256)];
        else              v = Ws[k * 64  + (c - 384)];
        Bt[idx] = (_Float16)v;
    }
    if (idx < NCOLS) {
        float b;
        if      (idx < 128) b = bq[idx] * 0.125f;
        else if (idx < 256) b = bk[idx - 128];
        else if (idx < 384) b = bv[idx - 256];
        else                b = bs[idx - 384];
        bcat[idx] = b;
    }
}

// ---------------------------------------------------------------------------
// MFMA GEMM body: one wave = 16 rows x NT*16 cols, fp32 accum.
// B-frags from XOR-swizzled LDS (byte ^ (row&7)<<4, same involution as the
// staging writes). A-frag: one 16B global load per lane per k-step.
// C/D mapping: row=(lane>>4)*4+reg, col=lane&15 (m89-verified).
// ---------------------------------------------------------------------------
template<int K, int NT>
__device__ __forceinline__ void gemm_body(
    const _Float16* __restrict__ Ah, const float* __restrict__ bias,
    float* __restrict__ qs, __half* __restrict__ kvh,
    const _Float16* Bs, int M, int colBase, int chunkRow0, int tid)
{
    int lane = tid & 63;
    int w    = tid >> 6;              // 0..7
    int fr   = lane & 15;
    int g    = lane >> 4;
    int row0 = chunkRow0 + w * 16;
    int arow = row0 + fr;
    if (arow > M - 1) arow = M - 1;   // clamp (stores guarded)

    f32x4 acc[NT];
    #pragma unroll
    for (int c = 0; c < NT; ++c) acc[c] = (f32x4){0.f, 0.f, 0.f, 0.f};

    #pragma unroll
    for (int ks = 0; ks < K / 32; ++ks) {
        int k0 = ks * 32 + g * 8;
        half8 af = *(const half8*)&Ah[(size_t)arow * K + k0];
        #pragma unroll
        for (int c = 0; c < NT; ++c) {
            int rl   = c * 16 + fr;
            int byte = rl * (K * 2) + k0 * 2;
            int sw   = byte ^ ((rl & 7) << 4);
            half8 bf = *(const half8*)((const char*)Bs + sw);
            acc[c] = __builtin_amdgcn_mfma_f32_16x16x32_f16(af, bf, acc[c], 0, 0, 0);
        }
    }

    #pragma unroll
    for (int c = 0; c < NT; ++c) {
        int col = colBase + c * 16 + fr;
        float bs = bias[col];
        #pragma unroll
        for (int j = 0; j < 4; ++j) {
            int row = row0 + g * 4 + j;
            if (row >= M) continue;
            float o = acc[c][j] + bs;
            if (col < 128) {
                qs[(size_t)row * QS_COLS + col] = o;
            } else if (col >= 384) {
                qs[(size_t)row * QS_COLS + 128 + (col - 384)] = o;
            } else {
                int cc  = col - 128;
                int mat = cc >> 7;          // 0=k, 1=v
                int hh  = (cc >> 6) & 1;
                int d   = cc & 63;
                int pos = mat * 128 + (d >> 2) * 8 + hh * 4 + (d & 3);
                kvh[(size_t)row * KV_COLS + pos] = __float2half_rn(o);
            }
        }
    }
}

// ---------------------------------------------------------------------------
// MFMA GEMM kernel: 512 threads = 8 waves, chunk = 128 rows.
// Column-split: blockIdx.x&1==0 -> q+k (cols 0..255, Bs 64KB @K=128);
//               ==1 -> v+skip (cols 256..447, 48KB). 2 blocks/CU co-resident
// (launch_bounds(512,4) caps VGPR<=128) -> 16 waves/CU.
// ---------------------------------------------------------------------------
template<int K>
__global__ __launch_bounds__(512, 4) void gemm_mfma_kernel(
    const _Float16* __restrict__ Ah,   // [M][K]
    const _Float16* __restrict__ Bt,   // [448][K]
    const float* __restrict__ bias,    // [448]
    float* __restrict__ qs, __half* __restrict__ kvh, int M)
{
    __shared__ _Float16 Bs[256 * K];   // 64KB (K=128) / 32KB (K=64)

    int tid    = threadIdx.x;
    int colblk = blockIdx.x & 1;
    int chunk  = blockIdx.x >> 1;
    int colBase = colblk ? 256 : 0;
    int cols    = colblk ? 192 : 256;

    // stage B panel with swizzle: dest_byte = src_byte ^ ((row&7)<<4)
    int bytes = cols * K * 2;
    const char* src = (const char*)Bt + (size_t)colBase * K * 2;
    for (int i = tid * 16; i < bytes; i += 512 * 16) {
        int rl = i / (K * 2);
        int sw = i ^ ((rl & 7) << 4);
        *(half8*)((char*)Bs + sw) = *(const half8*)(src + i);
    }
    __syncthreads();

    if (colblk == 0)
        gemm_body<K, 16>(Ah, bias, qs, kvh, Bs, M, 0,   chunk * 128, tid);
    else
        gemm_body<K, 12>(Ah, bias, qs, kvh, Bs, M, 256, chunk * 128, tid);
}

// ---------------------------------------------------------------------------
// CSR build: histogram -> 3-kernel parallel scan -> scatter
// ---------------------------------------------------------------------------
__global__ void hist_kernel(const int* __restrict__ dst, int* __restrict__ counts, int E)
{
    int i = blockIdx.x * 256 + threadIdx.x;
    if (i < E) atomicAdd(&counts[dst[i]], 1);
}

__global__ __launch_bounds__(256) void block_reduce_kernel(
    const int* __restrict__ counts, int* __restrict__ bsum, int N)
{
    __shared__ int s[256];
    int t = threadIdx.x;
    int i = blockIdx.x * 256 + t;
    s[t] = (i < N) ? counts[i] : 0;
    __syncthreads();
    #pragma unroll
    for (int o = 128; o; o >>= 1) {
        if (t < o) s[t] += s[t + o];
        __syncthreads();
    }
    if (t == 0) bsum[blockIdx.x] = s[0];
}

__global__ __launch_bounds__(256) void scan_partials_kernel(
    const int* __restrict__ bsum, int* __restrict__ boff, int nb, int* __restrict__ rowN)
{
    __shared__ int s[256];
    int t = threadIdx.x;
    int v = (t < nb) ? bsum[t] : 0;
    s[t] = v;
    __syncthreads();
    #pragma unroll
    for (int o = 1; o < 256; o <<= 1) {
        int x = (t >= o) ? s[t - o] : 0;
        __syncthreads();
        s[t] += x;
        __syncthreads();
    }
    if (t < nb) boff[t] = s[t] - v;     // exclusive
    if (t == nb - 1) rowN[0] = s[t];    // total = row_ptr[N]
}

__global__ __launch_bounds__(256) void block_scan_kernel(
    const int* __restrict__ counts, const int* __restrict__ boff,
    int* __restrict__ row_ptr, int* __restrict__ cursor, int N)
{
    __shared__ int s[256];
    int t = threadIdx.x;
    int i = blockIdx.x * 256 + t;
    int v = (i < N) ? counts[i] : 0;
    s[t] = v;
    __syncthreads();
    #pragma unroll
    for (int o = 1; o < 256; o <<= 1) {
        int x = (t >= o) ? s[t - o] : 0;
        __syncthreads();
        s[t] += x;
        __syncthreads();
    }
    if (i < N) {
        int excl = s[t] - v + boff[blockIdx.x];
        row_ptr[i] = excl;
        cursor[i]  = excl;
    }
}

__global__ void scatter_kernel(const int* __restrict__ ei, int* __restrict__ cursor,
                               int* __restrict__ src_sorted, int E)
{
    int i = blockIdx.x * 256 + threadIdx.x;
    if (i < E) {
        int d = ei[E + i];                    // dst
        int pos = atomicAdd(&cursor[d], 1);
        src_sorted[pos] = ei[i];              // src
    }
}

// ---------------------------------------------------------------------------
// DPP 16-lane sum (pure VALU)
// ---------------------------------------------------------------------------
__device__ __forceinline__ float dpp_sum16(float x)
{
    float t;
    t = __int_as_float(__builtin_amdgcn_mov_dpp(__float_as_int(x), 0xB1,  0xF, 0xF, true)); x += t; // xor 1
    t = __int_as_float(__builtin_amdgcn_mov_dpp(__float_as_int(x), 0x4E,  0xF, 0xF, true)); x += t; // xor 2
    t = __int_as_float(__builtin_amdgcn_mov_dpp(__float_as_int(x), 0x141, 0xF, 0xF, true)); x += t; // half-mirror
    t = __int_as_float(__builtin_amdgcn_mov_dpp(__float_as_int(x), 0x140, 0xF, 0xF, true)); x += t; // row-mirror
    return x;
}

// ---------------------------------------------------------------------------
// Fused edge kernel: one wave per dst node, 4 edge-groups x 16 lanes.
// Direct src_sorted[e] index loads (NO shfl preload — R4/R5 bug).
// fp16 K/V gathers: 2 x uint4 per lane per edge. Register double-buffer,
// DPP dot-reduce, flash merge, head-mean+skip+ReLU+LN.
// Writes h fp32 (pool) AND hh fp16 (next layer's GEMM A).
// ---------------------------------------------------------------------------
__global__ __launch_bounds__(256) void edge_conv_kernel(
    const float* __restrict__ qs, const __half* __restrict__ kvh,
    const int* __restrict__ row_ptr, const int* __restrict__ src_sorted,
    const float* __restrict__ gamma, const float* __restrict__ beta,
    float* __restrict__ hout, _Float16* __restrict__ hh, int N, int do_ln)
{
    int wave = threadIdx.x >> 6;
    int lane = threadIdx.x & 63;
    int g    = lane >> 4;        // edge-group 0..3
    int sub  = lane & 15;        // dim-chunk 0..15 (4 dims each)
    int node = blockIdx.x * 4 + wave;
    if (node >= N) return;

    const float* qb = qs + (size_t)node * QS_COLS;
    float4 q0 = *(const float4*)&qb[sub * 4];        // pre-scaled by 1/8
    float4 q1 = *(const float4*)&qb[64 + sub * 4];

    int e0 = row_ptr[node], e1 = row_ptr[node + 1];
    int deg = e1 - e0;

    float  m0 = -1e30f, m1 = -1e30f;
    float  s0 = 0.f, s1 = 0.f;
    float4 a0 = make_float4(0.f, 0.f, 0.f, 0.f);
    float4 a1 = make_float4(0.f, 0.f, 0.f, 0.f);

    int  e    = e0 + g;
    bool have = (e < e1);
    uint4 kraw, vraw;
    if (have) {
        int j = src_sorted[e];
        const __half* jb = kvh + (size_t)j * KV_COLS;
        kraw = *(const uint4*)&jb[sub * 8];
        vraw = *(const uint4*)&jb[128 + sub * 8];
    }

    while (have) {
        int  en    = e + 4;
        bool haven = (en < e1);
        uint4 krn, vrn;
        if (haven) {
            int jn = src_sorted[en];
            const __half* jbn = kvh + (size_t)jn * KV_COLS;
            krn = *(const uint4*)&jbn[sub * 8];
            vrn = *(const uint4*)&jbn[128 + sub * 8];
        }

        // unpack current K: 8 halves = k0(4 dims) | k1(4 dims)
        const __half2* kp = (const __half2*)&kraw;
        float2 ka = __half22float2(kp[0]), kb = __half22float2(kp[1]);
        float2 kc = __half22float2(kp[2]), kd = __half22float2(kp[3]);

        float p0 = fmaf(q0.w, kb.y, fmaf(q0.z, kb.x, fmaf(q0.y, ka.y, q0.x * ka.x)));
        float p1 = fmaf(q1.w, kd.y, fmaf(q1.z, kd.x, fmaf(q1.y, kc.y, q1.x * kc.x)));
        float sc0 = dpp_sum16(p0);
        float sc1 = dpp_sum16(p1);

        const __half2* vp = (const __half2*)&vraw;
        float2 va = __half22float2(vp[0]), vb = __half22float2(vp[1]);
        float2 vc = __half22float2(vp[2]), vd = __half22float2(vp[3]);

        float nm0 = fmaxf(m0, sc0);
        float f0  = __expf(m0 - nm0);
        float w0  = __expf(sc0 - nm0);
        s0 = fmaf(s0, f0, w0);
        a0.x = fmaf(a0.x, f0, w0 * va.x);
        a0.y = fmaf(a0.y, f0, w0 * va.y);
        a0.z = fmaf(a0.z, f0, w0 * vb.x);
        a0.w = fmaf(a0.w, f0, w0 * vb.y);
        m0 = nm0;

        float nm1 = fmaxf(m1, sc1);
        float f1  = __expf(m1 - nm1);
        float w1  = __expf(sc1 - nm1);
        s1 = fmaf(s1, f1, w1);
        a1.x = fmaf(a1.x, f1, w1 * vc.x);
        a1.y = fmaf(a1.y, f1, w1 * vc.y);
        a1.z = fmaf(a1.z, f1, w1 * vd.x);
        a1.w = fmaf(a1.w, f1, w1 * vd.y);
        m1 = nm1;

        kraw = krn; vraw = vrn; e = en; have = haven;
    }

    // merge flash states across the 4 groups (xor 16, then 32)
    #pragma unroll
    for (int offm = 16; offm <= 32; offm <<= 1) {
        float mo0 = __shfl_xor(m0, offm);
        float so0 = __shfl_xor(s0, offm);
        float4 ao0;
        ao0.x = __shfl_xor(a0.x, offm); ao0.y = __shfl_xor(a0.y, offm);
        ao0.z = __shfl_xor(a0.z, offm); ao0.w = __shfl_xor(a0.w, offm);
        float nm = fmaxf(m0, mo0);
        float fa = __expf(m0 - nm), fb = __expf(mo0 - nm);
        s0 = s0 * fa + so0 * fb;
        a0.x = a0.x * fa + ao0.x * fb; a0.y = a0.y * fa + ao0.y * fb;
        a0.z = a0.z * fa + ao0.z * fb; a0.w = a0.w * fa + ao0.w * fb;
        m0 = nm;

        float mo1 = __shfl_xor(m1, offm);
        float so1 = __shfl_xor(s1, offm);
        float4 ao1;
        ao1.x = __shfl_xor(a1.x, offm); ao1.y = __shfl_xor(a1.y, offm);
        ao1.z = __shfl_xor(a1.z, offm); ao1.w = __shfl_xor(a1.w, offm);
        nm = fmaxf(m1, mo1);
        fa = __expf(m1 - nm); fb = __expf(mo1 - nm);
        s1 = s1 * fa + so1 * fb;
        a1.x = a1.x * fa + ao1.x * fb; a1.y = a1.y * fa + ao1.y * fb;
        a1.z = a1.z * fa + ao1.z * fb; a1.w = a1.w * fa + ao1.w * fb;
        m1 = nm;
    }

    float4 skip = *(const float4*)&qb[128 + sub * 4];
    float4 o;
    if (deg > 0) {
        float r0 = 0.5f / s0, r1 = 0.5f / s1;
        o.x = a0.x * r0 + a1.x * r1 + skip.x;
        o.y = a0.y * r0 + a1.y * r1 + skip.y;
        o.z = a0.z * r0 + a1.z * r1 + skip.z;
        o.w = a0.w * r0 + a1.w * r1 + skip.w;
    } else {
        o = skip;
    }
    o.x = fmaxf(o.x, 0.f); o.y = fmaxf(o.y, 0.f);
    o.z = fmaxf(o.z, 0.f); o.w = fmaxf(o.w, 0.f);

    if (do_ln) {
        float mu = dpp_sum16(o.x + o.y + o.z + o.w) * (1.0f / 64.0f);
        float dx = o.x - mu, dy = o.y - mu, dz = o.z - mu, dw = o.w - mu;
        float var = dpp_sum16(dx * dx + dy * dy + dz * dz + dw * dw) * (1.0f / 64.0f);
        float rs = rsqrtf(var + LN_EPS);
        float4 gm = *(const float4*)&gamma[sub * 4];
        float4 bt = *(const float4*)&beta[sub * 4];
        o.x = dx * rs * gm.x + bt.x;
        o.y = dy * rs * gm.y + bt.y;
        o.z = dz * rs * gm.z + bt.z;
        o.w = dw * rs * gm.w + bt.w;
    }
    if (g == 0) {
        *(float4*)&hout[(size_t)node * HIDDEN + sub * 4] = o;
        __half2 h01 = __floats2half2_rn(o.x, o.y);
        __half2 h23 = __floats2half2_rn(o.z, o.w);
        uint2 pk;
        pk.x = *(unsigned int*)&h01;
        pk.y = *(unsigned int*)&h23;
        *(uint2*)&hh[(size_t)node * HIDDEN + sub * 4] = pk;
    }
}

// ---------------------------------------------------------------------------
// Pooling: batch sorted. One wave per 32 nodes (1563 waves, ~6/CU).
// Fast path (chunk within one graph, ~96% of chunks): branch-free unrolled
// sum of 32 rows (independent loads -> latency hidden), single atomic flush.
// Slow path at graph boundaries: serial scan.
// ---------------------------------------------------------------------------
#define POOL_CHUNK 32
__global__ __launch_bounds__(64) void pool_kernel(const float* __restrict__ h,
                                                  const int* __restrict__ batch,
                                                  float* __restrict__ pooled,
                                                  float* __restrict__ cnt, int N)
{
    int lane = threadIdx.x;
    int start = blockIdx.x * POOL_CHUNK;
    if (start >= N) return;
    int end = min(start + POOL_CHUNK, N);
    int b0 = batch[start];
    int b1 = batch[end - 1];

    if (b0 == b1) {
        float acc = 0.f;
        #pragma unroll 4
        for (int i = start; i < end; ++i)
            acc += h[(size_t)i * HIDDEN + lane];
        atomicAdd(&pooled[b0 * HIDDEN + lane], acc);
        if (lane == 0) atomicAdd(&cnt[b0], (float)(end - start));
    } else {
        float acc = 0.f;
        int cur = b0, c = 0;
        for (int i = start; i < end; ++i) {
            int b = batch[i];
            if (b != cur) {
                atomicAdd(&pooled[cur * HIDDEN + lane], acc);
                if (lane == 0) atomicAdd(&cnt[cur], (float)c);
                acc = 0.f; c = 0; cur = b;
            }
            acc += h[(size_t)i * HIDDEN + lane];
            ++c;
        }
        atomicAdd(&pooled[cur * HIDDEN + lane], acc);
        if (lane == 0) atomicAdd(&cnt[cur], (float)c);
    }
}

__global__ void final_kernel(const float* __restrict__ pooled, const float* __restrict__ cnt,
                             const float* __restrict__ Wp, const float* __restrict__ bp,
                             float* __restrict__ out)
{
    int g = threadIdx.x;   // 64 graphs
    float c = fmaxf(cnt[g], 1.0f);
    float s = 0.f;
    for (int d = 0; d < HIDDEN; ++d) s += pooled[g * HIDDEN + d] * Wp[d];
    out[g] = s / c + bp[0];
}

// ---------------------------------------------------------------------------
// Host launcher
// ---------------------------------------------------------------------------
extern "C" void kernel_launch(void* const* d_in, const int* in_sizes, int n_in,
                              void* d_out, int out_size, void* d_ws, size_t ws_size,
                              hipStream_t stream)
{
    const float* x    = (const float*)d_in[0];
    const int*   ei   = (const int*)d_in[1];
    const int*   batch= (const int*)d_in[2];

    const float* Wl[3][4];  // Wq, Wk, Wv, Ws
    const float* bl[3][4];  // bq, bk, bv, bs
    for (int l = 0; l < 3; ++l) {
        int b = 3 + l * 8;
        Wl[l][0] = (const float*)d_in[b + 0]; bl[l][0] = (const float*)d_in[b + 1];
        Wl[l][1] = (const float*)d_in[b + 2]; bl[l][1] = (const float*)d_in[b + 3];
        Wl[l][2] = (const float*)d_in[b + 4]; bl[l][2] = (const float*)d_in[b + 5];
        Wl[l][3] = (const float*)d_in[b + 6]; bl[l][3] = (const float*)d_in[b + 7];
    }
    const float* g0    = (const float*)d_in[27];
    const float* beta0 = (const float*)d_in[28];
    const float* g1    = (const float*)d_in[29];
    const float* beta1 = (const float*)d_in[30];
    const float* Wp    = (const float*)d_in[31];
    const float* bp    = (const float*)d_in[32];

    const int N = in_sizes[0] / 128;   // 50000
    const int E = in_sizes[1] / 2;     // 800000

    // workspace carve (256B aligned)
    size_t off = 0;
    auto carve = [&](size_t bytes) -> char* {
        char* p = (char*)d_ws + off;
        off = (off + bytes + 255) & ~(size_t)255;
        return p;
    };
    float*     qs     = (float*)carve((size_t)N * QS_COLS * 4);
    __half*    kvh    = (__half*)carve((size_t)N * KV_COLS * 2);
    float*     h      = (float*)carve((size_t)N * HIDDEN * 4);
    _Float16*  hh     = (_Float16*)carve((size_t)N * HIDDEN * 2);
    _Float16*  xh     = (_Float16*)carve((size_t)N * 128 * 2);
    _Float16*  Bt     = (_Float16*)carve((size_t)NCOLS * 128 * 2);
    float*     bcat   = (float*)carve(NCOLS * 4);
    int*       counts = (int*)carve((size_t)N * 4);
    int*       row_ptr= (int*)carve((size_t)(N + 1) * 4);
    int*       cursor = (int*)carve((size_t)N * 4);
    int*       src_sorted = (int*)carve((size_t)E * 4);
    int*       bsum   = (int*)carve(1024 * 4);
    int*       boff   = (int*)carve(1024 * 4);
    float*     pooled = (float*)carve((size_t)(N_GRAPHS * HIDDEN + N_GRAPHS) * 4);
    float*     cntf   = pooled + N_GRAPHS * HIDDEN;

    const int nb = (N + 255) / 256;    // 196 scan blocks

    // ---- CSR build (dst is layer-invariant) ----
    hipMemsetAsync(counts, 0, (size_t)N * 4, stream);
    hist_kernel<<<(E + 255) / 256, 256, 0, stream>>>(ei + E, counts, E);
    block_reduce_kernel<<<nb, 256, 0, stream>>>(counts, bsum, N);
    scan_partials_kernel<<<1, 256, 0, stream>>>(bsum, boff, nb, &row_ptr[N]);
    block_scan_kernel<<<nb, 256, 0, stream>>>(counts, boff, row_ptr, cursor, N);
    scatter_kernel<<<(E + 255) / 256, 256, 0, stream>>>(ei, cursor, src_sorted, E);

    // ---- cast x to fp16 once ----
    {
        int n4 = (N * 128) / 4;
        cast_f2h_kernel<<<(n4 + 255) / 256, 256, 0, stream>>>(x, xh, n4);
    }

    const int gemm_grid = 2 * ((N + 127) / 128);   // 2 col-blocks x 391 row-chunks

    // ---- 3 TransformerConv layers ----
    for (int l = 0; l < 3; ++l) {
        int K = (l == 0) ? 128 : 64;
        int packTot = NCOLS * K;
        pack_kernel<<<(packTot + 255) / 256, 256, 0, stream>>>(
            Wl[l][0], Wl[l][1], Wl[l][2], Wl[l][3],
            bl[l][0], bl[l][1], bl[l][2], bl[l][3], Bt, bcat, K);
        if (l == 0)
            gemm_mfma_kernel<128><<<gemm_grid, 512, 0, stream>>>(xh, Bt, bcat, qs, kvh, N);
        else
            gemm_mfma_kernel<64><<<gemm_grid, 512, 0, stream>>>(hh, Bt, bcat, qs, kvh, N);
        int do_ln = (l < 2) ? 1 : 0;
        const float* gg = (l == 0) ? g0 : g1;
        const float* bb = (l == 0) ? beta0 : beta1;
        edge_conv_kernel<<<(N + 3) / 4, 256, 0, stream>>>(
            qs, kvh, row_ptr, src_sorted, gg, bb, h, hh, N, do_ln);
    }

    // ---- global mean pool + head ----
    hipMemsetAsync(pooled, 0, (size_t)(N_GRAPHS * HIDDEN + N_GRAPHS) * 4, stream);
    pool_kernel<<<(N + POOL_CHUNK - 1) / POOL_CHUNK, 64, 0, stream>>>(h, batch, pooled, cntf, N);
    final_kernel<<<1, 64, 0, stream>>>(pooled, cntf, Wp, bp, (float*)d_out);
}